// Round 9
// baseline (260.629 us; speedup 1.0000x reference)
//
#include <hip/hip_runtime.h>
#include <cstdint>
#include <cstddef>

typedef unsigned short u16;
typedef unsigned int u32;
typedef __bf16 bf16x8 __attribute__((ext_vector_type(8)));
typedef float f32x4 __attribute__((ext_vector_type(4)));
typedef u32 u32x4 __attribute__((ext_vector_type(4)));
typedef u32 u32x2 __attribute__((ext_vector_type(2)));
typedef unsigned short u16x8 __attribute__((ext_vector_type(8)));
typedef short s16x4 __attribute__((ext_vector_type(4)));

#if __has_builtin(__builtin_amdgcn_mfma_f32_16x16x16bf16_1k)
#define HAVE_MFMA16 1
#else
#define HAVE_MFMA16 0
#endif

// f32 -> bf16 round-to-nearest-even (finite inputs only)
__device__ __forceinline__ u16 f2bf(float f) {
    u32 u = __float_as_uint(f);
    u += 0x7fffu + ((u >> 16) & 1u);
    return (u16)(u >> 16);
}

// async global->LDS, 16B per lane. LDS ptr must be wave-uniform; HW adds lane*16.
__device__ __forceinline__ void gl16(const void* g, void* l) {
    __builtin_amdgcn_global_load_lds(
        (const __attribute__((address_space(1))) unsigned int*)g,
        (__attribute__((address_space(3))) unsigned int*)l, 16, 0, 0);
}

// ---------------------------------------------------------------- conversions
__global__ __launch_bounds__(256) void cvt_x_k(const float* __restrict__ x,
                                               u16* __restrict__ o) {
    int i = blockIdx.x * 256 + threadIdx.x;
    const float4* xv = (const float4*)x;
    float4 a = xv[2 * i], b = xv[2 * i + 1];
    ushort4 r0, r1;
    r0.x = f2bf(a.x); r0.y = f2bf(a.y); r0.z = f2bf(a.z); r0.w = f2bf(a.w);
    r1.x = f2bf(b.x); r1.y = f2bf(b.y); r1.z = f2bf(b.z); r1.w = f2bf(b.w);
    ((ushort4*)o)[2 * i] = r0;
    ((ushort4*)o)[2 * i + 1] = r1;
}

// W [1024][1024] f32 row-major (k,n) -> out [1024][1024] bf16 (n,k)  (i.e. W^T)
__global__ __launch_bounds__(256) void cvt_wT_k(const float* __restrict__ W,
                                                u16* __restrict__ o) {
    __shared__ float tile[64][65];
    const int bx = blockIdx.x, by = blockIdx.y;
    const int t = threadIdx.x, tn = t & 63, tr = t >> 6;
#pragma unroll
    for (int r = 0; r < 16; ++r) {
        int kk = r * 4 + tr;
        tile[kk][tn] = W[(size_t)(by * 64 + kk) * 1024 + bx * 64 + tn];
    }
    __syncthreads();
#pragma unroll
    for (int r = 0; r < 16; ++r) {
        int nn = r * 4 + tr;
        o[(size_t)(bx * 64 + nn) * 1024 + by * 64 + tn] = f2bf(tile[tn][nn]);
    }
}

// ---------------------------------------------------------------- GEMM 128x128
// A [M][1024] bf16 row-major, Bt [N][1024] bf16 (= B^T), K=1024.
// 3-buffer depth-2 counted-vmcnt pipeline (T4):
//   iter t: vmcnt(4); barrier; stage(t+2); compute(t)
// MODE 0: fused QKV epilogue -> q (pre-scaled by 0.125*log2e), k as
//         [BH][2048][64], v transposed [BH][64][2048]
// MODE 1: f32 out [M][1024] + bias
template <int MODE>
__global__ __launch_bounds__(256) void gemm_k(
    const u16* __restrict__ A, const u16* __restrict__ Bt,
    const float* __restrict__ bias0, const float* __restrict__ bias1,
    const float* __restrict__ bias2,
    u16* __restrict__ oq, u16* __restrict__ ok_, u16* __restrict__ ov,
    float* __restrict__ oc) {
    __shared__ __align__(16) u16 As[3 * 128 * 32];   // 24KB
    __shared__ __align__(16) u16 Bs[3 * 128 * 32];   // 24KB
    const int t = threadIdx.x, w = t >> 6, lane = t & 63;
    const int lr = lane & 15, lg = lane >> 4;
    const int brow = blockIdx.x * 128, bcol = blockIdx.y * 128;
    const int wr = w >> 1, wc = w & 1;
    const char* Ab = (const char*)A + (size_t)brow * 2048;
    const char* Bb = (const char*)Bt + (size_t)bcol * 2048;
    const int lrow = lane >> 2, lcol = (lane & 3) << 4;
    // per-wave staging rows (16 rows x 64B per gl16 instruction)
    const int r0a = w * 32, r0b = w * 32 + 16;
    const size_t ga = (size_t)(r0a + lrow) * 2048 + lcol;
    const size_t gb = (size_t)(r0b + lrow) * 2048 + lcol;

    f32x4 acc[4][4];
#pragma unroll
    for (int m = 0; m < 4; ++m)
#pragma unroll
        for (int n = 0; n < 4; ++n) acc[m][n] = (f32x4){0.f, 0.f, 0.f, 0.f};

    // prologue: stage K-steps 0 and 1 into buffers 0,1 (issue order matters)
    gl16(Ab + ga, (char*)As + r0a * 64);
    gl16(Ab + gb, (char*)As + r0b * 64);
    gl16(Bb + ga, (char*)Bs + r0a * 64);
    gl16(Bb + gb, (char*)Bs + r0b * 64);
    gl16(Ab + ga + 64, (char*)As + 8192 + r0a * 64);
    gl16(Ab + gb + 64, (char*)As + 8192 + r0b * 64);
    gl16(Bb + ga + 64, (char*)Bs + 8192 + r0a * 64);
    gl16(Bb + gb + 64, (char*)Bs + 8192 + r0b * 64);

    for (int tt = 0; tt < 32; ++tt) {
        if (tt < 31) {
            asm volatile("s_waitcnt vmcnt(4)" ::: "memory");
        } else {
            asm volatile("s_waitcnt vmcnt(0)" ::: "memory");
        }
        __builtin_amdgcn_s_barrier();
        __builtin_amdgcn_sched_barrier(0);
        if (tt < 30) {   // stage K-step t+2 into buffer (t+2)%3
            const int nb = (tt + 2) % 3;
            const size_t ko = (size_t)(tt + 2) * 64;   // 32 elems * 2B
            char* Asn = (char*)As + nb * 8192;
            char* Bsn = (char*)Bs + nb * 8192;
            gl16(Ab + ga + ko, Asn + r0a * 64);
            gl16(Ab + gb + ko, Asn + r0b * 64);
            gl16(Bb + ga + ko, Bsn + r0a * 64);
            gl16(Bb + gb + ko, Bsn + r0b * 64);
        }
        const char* AsB = (const char*)As + (tt % 3) * 8192;
        const char* BsB = (const char*)Bs + (tt % 3) * 8192;
        bf16x8 af[4], bfr[4];
#pragma unroll
        for (int m = 0; m < 4; ++m)
            af[m] = *(const bf16x8*)(AsB + (wr * 64 + m * 16 + lr) * 64 + lg * 16);
#pragma unroll
        for (int n = 0; n < 4; ++n)
            bfr[n] = *(const bf16x8*)(BsB + (wc * 64 + n * 16 + lr) * 64 + lg * 16);
#pragma unroll
        for (int m = 0; m < 4; ++m)
#pragma unroll
            for (int n = 0; n < 4; ++n)
                acc[m][n] = __builtin_amdgcn_mfma_f32_16x16x32_bf16(af[m], bfr[n],
                                                                    acc[m][n], 0, 0, 0);
    }

    const float QSCALE = 0.125f * 1.44269504f;
#pragma unroll
    for (int n = 0; n < 4; ++n) {
        const int col = bcol + wc * 64 + n * 16 + lr;
        if (MODE == 0) {
#pragma unroll
            for (int m = 0; m < 4; ++m)
#pragma unroll
                for (int r = 0; r < 4; ++r) {
                    int row = brow + wr * 64 + m * 16 + 4 * lg + r;
                    int b = row >> 11, l = row & 2047;
                    float val = acc[m][n][r];
                    if (col < 1024) {
                        int hh = col >> 6, d = col & 63;
                        oq[(((size_t)b * 16 + hh) * 2048 + l) * 64 + d] =
                            f2bf((val + bias0[col]) * QSCALE);
                    } else if (col < 2048) {
                        int c = col - 1024, hh = c >> 6, d = c & 63;
                        ok_[(((size_t)b * 16 + hh) * 2048 + l) * 64 + d] =
                            f2bf(val + bias1[c]);
                    } else {
                        int c = col - 2048, hh = c >> 6, d = c & 63;
                        ov[(((size_t)b * 16 + hh) * 64 + d) * 2048 + l] =
                            f2bf(val + bias2[c]);
                    }
                }
        } else {
            const float bb = bias0[col];
#pragma unroll
            for (int m = 0; m < 4; ++m)
#pragma unroll
                for (int r = 0; r < 4; ++r) {
                    int row = brow + wr * 64 + m * 16 + 4 * lg + r;
                    oc[(size_t)row * 1024 + col] = acc[m][n][r] + bb;
                }
        }
    }
}

// ---------------------------------------------------------------- attention
// q (pre-scaled by 0.125*log2e), k: [BH][2048][64] bf16; vt: [BH][64][2048]
// ao: [B*2048][1024] bf16
// BARRIER-FREE: K/V fragments read directly from global (L2-resident per
// XCD after swizzle; per-head K+V = 512KB). No staging, no in-loop LDS,
// waves free-run. Each wave owns 32 q-rows (sub-blocks A,B sharing every
// K/V fragment). MAX-FREE softmax: full exponent (ALiBi-static baseline +
// sl2*j0) accumulates in the MFMA C-init abF2 (+= ainc per tile).
// PV: 16x16x16 MFMA whose B-frag layout == S^T C-layout (no P exchange).
__global__ __launch_bounds__(256, 2) void attn_k(const u16* __restrict__ qg_,
                                                 const u16* __restrict__ kg_,
                                                 const u16* __restrict__ vg_,
                                                 u16* __restrict__ ao) {
    __shared__ __align__(16) u16 smem[4 * 32 * 72];   // 18KB epilogue scratch
    const int t = threadIdx.x, w = t >> 6, lane = t & 63;
    const int lr = lane & 15, lg = lane >> 4;
    // XCD swizzle over 512 blocks: bid%8 -> bh low bits (same-XCD blocks
    // share 4 heads' K/V ~ 2MB < 4MB L2)
    const int bid = blockIdx.y * 16 + blockIdx.x;
    const int qt = (bid >> 3) & 15;
    const int bh = ((bid >> 7) << 3) | (bid & 7);
    const int q0 = qt * 128, h = bh & 15, bb = bh >> 4;
    const float sl2 = exp2f(-0.5f * (float)(h + 1)) * 1.44269504f; // slope*log2e

    const char* khead = (const char*)(kg_ + (size_t)bh * 2048 * 64);
    const char* vhead = (const char*)(vg_ + (size_t)bh * 64 * 2048);

    // Q fragments straight from global, 32 rows per wave
    const char* qpA = (const char*)qg_ +
                      ((size_t)bh * 2048 + q0 + w * 32 + lr) * 128;
    bf16x8 qa0A = *(const bf16x8*)(qpA + lg * 16);
    bf16x8 qa1A = *(const bf16x8*)(qpA + 64 + lg * 16);
    bf16x8 qa0B = *(const bf16x8*)(qpA + 2048 + lg * 16);
    bf16x8 qa1B = *(const bf16x8*)(qpA + 2048 + 64 + lg * 16);

    // C-init carries the WHOLE exponent shift: sl2*(jloc-2047) - 16 + sl2*j0,
    // advanced by ainc = sl2*64 per tile (q-independent: shared by A and B).
    f32x4 abF2[4];
#pragma unroll
    for (int n = 0; n < 4; ++n)
#pragma unroll
        for (int r = 0; r < 4; ++r)
            abF2[n][r] = sl2 * (float)(n * 16 + 4 * lg + r - 2047) - 16.0f;
    const float ainc = sl2 * 64.0f;
    f32x4 oaccA[4], oaccB[4], l4A, l4B;
#pragma unroll
    for (int nn = 0; nn < 4; ++nn) {
        oaccA[nn] = (f32x4){0.f, 0.f, 0.f, 0.f};
        oaccB[nn] = (f32x4){0.f, 0.f, 0.f, 0.f};
    }
    l4A = (f32x4){0.f, 0.f, 0.f, 0.f};
    l4B = (f32x4){0.f, 0.f, 0.f, 0.f};
#if !HAVE_MFMA16
    const int srcA = lr + ((lg & 1) << 5);
    const int srcB = srcA + 16;
    const bool hiHalf = (lg >> 1) != 0;
#endif

    // per-lane base pointers (advance by fixed stride per tile)
    const char* krow = khead + (size_t)lr * 128;          // + n*2048 + tile*8192
    const char* vrow = vhead + (size_t)lr * 4096 + lg * 8; // + nn*65536 + n*32 + tile*128

    for (int tt = 0; tt < 32; ++tt) {
        const char* kj = krow + (size_t)tt * 8192;
        const char* vj = vrow + (size_t)tt * 128;

        // issue all K then V loads up front (V consumed ~200cy later -> hidden)
        bf16x8 kf0[4], kf1[4];
#pragma unroll
        for (int n = 0; n < 4; ++n) {
            kf0[n] = *(const bf16x8*)(kj + n * 2048 + lg * 16);
            kf1[n] = *(const bf16x8*)(kj + n * 2048 + 64 + lg * 16);
        }
#if HAVE_MFMA16
        s16x4 va_[4][4];
#pragma unroll
        for (int n = 0; n < 4; ++n)
#pragma unroll
            for (int nn = 0; nn < 4; ++nn)
                va_[n][nn] = *(const s16x4*)(vj + nn * 65536 + n * 32);
#endif

        // S^T = mfma(K, Q): each K fragment feeds BOTH q-sub-blocks
        f32x4 saA[4], saB[4];
        __builtin_amdgcn_s_setprio(1);
#pragma unroll
        for (int n = 0; n < 4; ++n) {
            saA[n] = __builtin_amdgcn_mfma_f32_16x16x32_bf16(kf0[n], qa0A, abF2[n],
                                                             0, 0, 0);
            saB[n] = __builtin_amdgcn_mfma_f32_16x16x32_bf16(kf0[n], qa0B, abF2[n],
                                                             0, 0, 0);
        }
#pragma unroll
        for (int n = 0; n < 4; ++n) {
            saA[n] = __builtin_amdgcn_mfma_f32_16x16x32_bf16(kf1[n], qa1A, saA[n],
                                                             0, 0, 0);
            saB[n] = __builtin_amdgcn_mfma_f32_16x16x32_bf16(kf1[n], qa1B, saB[n],
                                                             0, 0, 0);
        }
        __builtin_amdgcn_s_setprio(0);

        // max-free softmax: P = exp2(sa); l-sums deferred to epilogue
#pragma unroll
        for (int n = 0; n < 4; ++n)
#pragma unroll
            for (int r = 0; r < 4; ++r) {
                saA[n][r] = exp2f(saA[n][r]);
                saB[n][r] = exp2f(saB[n][r]);
            }
#pragma unroll
        for (int n = 0; n < 4; ++n) { l4A += saA[n]; l4B += saB[n]; }
#pragma unroll
        for (int n = 0; n < 4; ++n) abF2[n] += ainc;

#if HAVE_MFMA16
        // pack P (C-layout) into 16x16x16 B-frags: col=q=lr, k=4lg+e == j-layout
        s16x4 pnA[4], pnB[4];
#pragma unroll
        for (int n = 0; n < 4; ++n) {
            u32 lo, hi;
            asm("v_cvt_pk_bf16_f32 %0, %1, %2"
                : "=v"(lo) : "v"(saA[n][0]), "v"(saA[n][1]));
            asm("v_cvt_pk_bf16_f32 %0, %1, %2"
                : "=v"(hi) : "v"(saA[n][2]), "v"(saA[n][3]));
            u32x2 tmpa = {lo, hi};
            pnA[n] = __builtin_bit_cast(s16x4, tmpa);
            asm("v_cvt_pk_bf16_f32 %0, %1, %2"
                : "=v"(lo) : "v"(saB[n][0]), "v"(saB[n][1]));
            asm("v_cvt_pk_bf16_f32 %0, %1, %2"
                : "=v"(hi) : "v"(saB[n][2]), "v"(saB[n][3]));
            u32x2 tmpb = {lo, hi};
            pnB[n] = __builtin_bit_cast(s16x4, tmpb);
        }
        // O^T += V^T * P: each V fragment feeds BOTH q-sub-blocks
        __builtin_amdgcn_s_setprio(1);
#pragma unroll
        for (int n = 0; n < 4; ++n)
#pragma unroll
            for (int nn = 0; nn < 4; ++nn) {
                oaccA[nn] = __builtin_amdgcn_mfma_f32_16x16x16bf16_1k(va_[n][nn],
                                                                      pnA[n],
                                                                      oaccA[nn],
                                                                      0, 0, 0);
                oaccB[nn] = __builtin_amdgcn_mfma_f32_16x16x16bf16_1k(va_[n][nn],
                                                                      pnB[n],
                                                                      oaccB[nn],
                                                                      0, 0, 0);
            }
        __builtin_amdgcn_s_setprio(0);
#else
        // fallback: exchange to 16x16x32 B-frag layout; V direct from global
        u32 pk[8];
        u32x4 pb0, pb1;
#pragma unroll
        for (int n = 0; n < 4; ++n)
#pragma unroll
            for (int rp = 0; rp < 2; ++rp) {
                u32 rpk;
                asm("v_cvt_pk_bf16_f32 %0, %1, %2"
                    : "=v"(rpk) : "v"(saA[n][2 * rp]), "v"(saA[n][2 * rp + 1]));
                pk[n * 2 + rp] = rpk;
            }
#pragma unroll
        for (int g = 0; g < 4; ++g) {
            int src = (g < 2) ? srcA : srcB;
            u32 a0 = (u32)__shfl((int)pk[0 + (g & 1)], src);
            u32 a1 = (u32)__shfl((int)pk[2 + (g & 1)], src);
            u32 b0 = (u32)__shfl((int)pk[4 + (g & 1)], src);
            u32 b1 = (u32)__shfl((int)pk[6 + (g & 1)], src);
            pb0[g] = hiHalf ? a1 : a0;
            pb1[g] = hiHalf ? b1 : b0;
        }
        {
            bf16x8 pf0 = __builtin_bit_cast(bf16x8, pb0);
            bf16x8 pf1 = __builtin_bit_cast(bf16x8, pb1);
#pragma unroll
            for (int nn = 0; nn < 4; ++nn) {
                bf16x8 vf0 = *(const bf16x8*)(vj - lg * 8 + nn * 65536 + lg * 16);
                oaccA[nn] = __builtin_amdgcn_mfma_f32_16x16x32_bf16(vf0, pf0,
                                                                    oaccA[nn], 0, 0, 0);
                bf16x8 vf1 = *(const bf16x8*)(vj - lg * 8 + nn * 65536 + 64 + lg * 16);
                oaccA[nn] = __builtin_amdgcn_mfma_f32_16x16x32_bf16(vf1, pf1,
                                                                    oaccA[nn], 0, 0, 0);
            }
        }
#pragma unroll
        for (int n = 0; n < 4; ++n)
#pragma unroll
            for (int rp = 0; rp < 2; ++rp) {
                u32 rpk;
                asm("v_cvt_pk_bf16_f32 %0, %1, %2"
                    : "=v"(rpk) : "v"(saB[n][2 * rp]), "v"(saB[n][2 * rp + 1]));
                pk[n * 2 + rp] = rpk;
            }
#pragma unroll
        for (int g = 0; g < 4; ++g) {
            int src = (g < 2) ? srcA : srcB;
            u32 a0 = (u32)__shfl((int)pk[0 + (g & 1)], src);
            u32 a1 = (u32)__shfl((int)pk[2 + (g & 1)], src);
            u32 b0 = (u32)__shfl((int)pk[4 + (g & 1)], src);
            u32 b1 = (u32)__shfl((int)pk[6 + (g & 1)], src);
            pb0[g] = hiHalf ? a1 : a0;
            pb1[g] = hiHalf ? b1 : b0;
        }
        {
            bf16x8 pf0 = __builtin_bit_cast(bf16x8, pb0);
            bf16x8 pf1 = __builtin_bit_cast(bf16x8, pb1);
#pragma unroll
            for (int nn = 0; nn < 4; ++nn) {
                bf16x8 vf0 = *(const bf16x8*)(vj - lg * 8 + nn * 65536 + lg * 16);
                oaccB[nn] = __builtin_amdgcn_mfma_f32_16x16x32_bf16(vf0, pf0,
                                                                    oaccB[nn], 0, 0, 0);
                bf16x8 vf1 = *(const bf16x8*)(vj - lg * 8 + nn * 65536 + 64 + lg * 16);
                oaccB[nn] = __builtin_amdgcn_mfma_f32_16x16x32_bf16(vf1, pf1,
                                                                    oaccB[nn], 0, 0, 0);
            }
        }
#endif
    }

    // epilogue: l reductions, normalize, transpose O^T -> O via per-wave LDS
    // scratch (32 rows x 72 u16 per wave; A/B halves disjoint).
    float lA = (l4A[0] + l4A[1]) + (l4A[2] + l4A[3]);
    lA += __shfl_xor(lA, 16);
    lA += __shfl_xor(lA, 32);
    float lB = (l4B[0] + l4B[1]) + (l4B[2] + l4B[3]);
    lB += __shfl_xor(lB, 16);
    lB += __shfl_xor(lB, 32);
    const float linvA = 1.0f / lA, linvB = 1.0f / lB;
    u16* ow = smem + w * (32 * 72);
#pragma unroll
    for (int nn = 0; nn < 4; ++nn)
#pragma unroll
        for (int r = 0; r < 4; ++r) {
            ow[lr * 72 + nn * 16 + 4 * lg + r] = f2bf(oaccA[nn][r] * linvA);
            ow[(16 + lr) * 72 + nn * 16 + 4 * lg + r] = f2bf(oaccB[nn][r] * linvB);
        }
    __syncthreads();
    const int q_ = lane >> 2, d0 = (lane & 3) << 4;
    const u16* orowA = smem + w * (32 * 72) + q_ * 72 + d0;
    const u16* orowB = orowA + 16 * 72;
    u16x8 a0 = *(const u16x8*)(orowA);
    u16x8 a1 = *(const u16x8*)(orowA + 8);
    u16x8 b0 = *(const u16x8*)(orowB);
    u16x8 b1 = *(const u16x8*)(orowB + 8);
    size_t gaddr = ((size_t)bb * 2048 + q0 + w * 32 + q_) * 1024 + h * 64 + d0;
    *(u16x8*)(ao + gaddr) = a0;
    *(u16x8*)(ao + gaddr + 8) = a1;
    *(u16x8*)(ao + gaddr + 16 * 1024) = b0;
    *(u16x8*)(ao + gaddr + 16 * 1024 + 8) = b1;
}

// ---------------------------------------------------------------- launch
extern "C" void kernel_launch(void* const* d_in, const int* in_sizes, int n_in,
                              void* d_out, int out_size, void* d_ws, size_t ws_size,
                              hipStream_t stream) {
    const float* x  = (const float*)d_in[0];
    const float* Wq = (const float*)d_in[1];
    const float* bq = (const float*)d_in[2];
    const float* Wk = (const float*)d_in[3];
    const float* bk = (const float*)d_in[4];
    const float* Wv = (const float*)d_in[5];
    const float* bv = (const float*)d_in[6];
    const float* Wo = (const float*)d_in[7];
    const float* bo = (const float*)d_in[8];

    const size_t MB = 1u << 20;
    if (ws_size < 40 * MB) return;
    char* ws = (char*)d_ws;
    u16* xb    = (u16*)(ws);             // 8MB  [4096][1024] bf16 (reused as ao)
    u16* wqkvt = (u16*)(ws + 8 * MB);    // 6MB  [3072][1024] = [Wq^T;Wk^T;Wv^T]
    u16* wot   = (u16*)(ws + 14 * MB);   // 2MB  Wo^T
    u16* qb    = (u16*)(ws + 16 * MB);   // 8MB  [32][2048][64]
    u16* kb    = (u16*)(ws + 24 * MB);   // 8MB  [32][2048][64]
    u16* vt    = (u16*)(ws + 32 * MB);   // 8MB  [32][64][2048]
    u16* ao    = xb;

    cvt_x_k<<<2048, 256, 0, stream>>>(x, xb);
    cvt_wT_k<<<dim3(16, 16), 256, 0, stream>>>(Wq, wqkvt);
    cvt_wT_k<<<dim3(16, 16), 256, 0, stream>>>(Wk, wqkvt + (1u << 20));
    cvt_wT_k<<<dim3(16, 16), 256, 0, stream>>>(Wv, wqkvt + (2u << 20));
    cvt_wT_k<<<dim3(16, 16), 256, 0, stream>>>(Wo, wot);

    gemm_k<0><<<dim3(32, 24), 256, 0, stream>>>(xb, wqkvt, bq, bk, bv,
                                                qb, kb, vt, nullptr);
    attn_k<<<dim3(16, 32), 256, 0, stream>>>(qb, kb, vt, ao);
    gemm_k<1><<<dim3(32, 8), 256, 0, stream>>>(ao, wot, bo, nullptr, nullptr,
                                               nullptr, nullptr, nullptr,
                                               (float*)d_out);
}

// Round 10
// 144.324 us; speedup vs baseline: 1.8059x; 1.8059x over previous
//
#include <hip/hip_runtime.h>
#include <cstdint>
#include <cstddef>

typedef unsigned short u16;
typedef unsigned int u32;
typedef __bf16 bf16x8 __attribute__((ext_vector_type(8)));
typedef float f32x4 __attribute__((ext_vector_type(4)));
typedef u32 u32x4 __attribute__((ext_vector_type(4)));
typedef u32 u32x2 __attribute__((ext_vector_type(2)));
typedef unsigned short u16x8 __attribute__((ext_vector_type(8)));
typedef short s16x4 __attribute__((ext_vector_type(4)));

#if __has_builtin(__builtin_amdgcn_mfma_f32_16x16x16bf16_1k)
#define HAVE_MFMA16 1
#else
#define HAVE_MFMA16 0
#endif

// f32 -> bf16 round-to-nearest-even (finite inputs only)
__device__ __forceinline__ u16 f2bf(float f) {
    u32 u = __float_as_uint(f);
    u += 0x7fffu + ((u >> 16) & 1u);
    return (u16)(u >> 16);
}

// async global->LDS, 16B per lane. LDS ptr must be wave-uniform; HW adds lane*16.
__device__ __forceinline__ void gl16(const void* g, void* l) {
    __builtin_amdgcn_global_load_lds(
        (const __attribute__((address_space(1))) unsigned int*)g,
        (__attribute__((address_space(3))) unsigned int*)l, 16, 0, 0);
}

// ---------------------------------------------------------------- conversions
__global__ __launch_bounds__(256) void cvt_x_k(const float* __restrict__ x,
                                               u16* __restrict__ o) {
    int i = blockIdx.x * 256 + threadIdx.x;
    const float4* xv = (const float4*)x;
    float4 a = xv[2 * i], b = xv[2 * i + 1];
    ushort4 r0, r1;
    r0.x = f2bf(a.x); r0.y = f2bf(a.y); r0.z = f2bf(a.z); r0.w = f2bf(a.w);
    r1.x = f2bf(b.x); r1.y = f2bf(b.y); r1.z = f2bf(b.z); r1.w = f2bf(b.w);
    ((ushort4*)o)[2 * i] = r0;
    ((ushort4*)o)[2 * i + 1] = r1;
}

// All four W [1024][1024] f32 (k,n) -> bf16 (n,k) transposes in ONE launch.
// blockIdx.z selects {Wq,Wk,Wv,Wo}.
__global__ __launch_bounds__(256) void cvt_wT4_k(const float* __restrict__ Wq,
                                                 const float* __restrict__ Wk,
                                                 const float* __restrict__ Wv,
                                                 const float* __restrict__ Wo,
                                                 u16* __restrict__ oqkv,
                                                 u16* __restrict__ oo) {
    __shared__ float tile[64][65];
    const int z = blockIdx.z;
    const float* W = (z == 0) ? Wq : (z == 1) ? Wk : (z == 2) ? Wv : Wo;
    u16* o = (z < 3) ? (oqkv + ((size_t)z << 20)) : oo;
    const int bx = blockIdx.x, by = blockIdx.y;
    const int t = threadIdx.x, tn = t & 63, tr = t >> 6;
#pragma unroll
    for (int r = 0; r < 16; ++r) {
        int kk = r * 4 + tr;
        tile[kk][tn] = W[(size_t)(by * 64 + kk) * 1024 + bx * 64 + tn];
    }
    __syncthreads();
#pragma unroll
    for (int r = 0; r < 16; ++r) {
        int nn = r * 4 + tr;
        o[(size_t)(bx * 64 + nn) * 1024 + by * 64 + tn] = f2bf(tile[tn][nn]);
    }
}

// ---------------------------------------------------------------- GEMM 128x128
// A [M][1024] bf16 row-major, Bt [N][1024] bf16 (= B^T), K=1024.
// 3-buffer depth-2 counted-vmcnt pipeline (T4):
//   iter t: vmcnt(4); barrier; stage(t+2); compute(t)
// MODE 0: fused QKV epilogue -> q (pre-scaled by 0.125*log2e), k as
//         [BH][2048][64], v transposed [BH][64][2048]
// MODE 1: f32 out [M][1024] + bias
template <int MODE>
__global__ __launch_bounds__(256) void gemm_k(
    const u16* __restrict__ A, const u16* __restrict__ Bt,
    const float* __restrict__ bias0, const float* __restrict__ bias1,
    const float* __restrict__ bias2,
    u16* __restrict__ oq, u16* __restrict__ ok_, u16* __restrict__ ov,
    float* __restrict__ oc) {
    __shared__ __align__(16) u16 As[3 * 128 * 32];   // 24KB
    __shared__ __align__(16) u16 Bs[3 * 128 * 32];   // 24KB
    const int t = threadIdx.x, w = t >> 6, lane = t & 63;
    const int lr = lane & 15, lg = lane >> 4;
    const int brow = blockIdx.x * 128, bcol = blockIdx.y * 128;
    const int wr = w >> 1, wc = w & 1;
    const char* Ab = (const char*)A + (size_t)brow * 2048;
    const char* Bb = (const char*)Bt + (size_t)bcol * 2048;
    const int lrow = lane >> 2, lcol = (lane & 3) << 4;
    // per-wave staging rows (16 rows x 64B per gl16 instruction)
    const int r0a = w * 32, r0b = w * 32 + 16;
    const size_t ga = (size_t)(r0a + lrow) * 2048 + lcol;
    const size_t gb = (size_t)(r0b + lrow) * 2048 + lcol;

    f32x4 acc[4][4];
#pragma unroll
    for (int m = 0; m < 4; ++m)
#pragma unroll
        for (int n = 0; n < 4; ++n) acc[m][n] = (f32x4){0.f, 0.f, 0.f, 0.f};

    // prologue: stage K-steps 0 and 1 into buffers 0,1 (issue order matters)
    gl16(Ab + ga, (char*)As + r0a * 64);
    gl16(Ab + gb, (char*)As + r0b * 64);
    gl16(Bb + ga, (char*)Bs + r0a * 64);
    gl16(Bb + gb, (char*)Bs + r0b * 64);
    gl16(Ab + ga + 64, (char*)As + 8192 + r0a * 64);
    gl16(Ab + gb + 64, (char*)As + 8192 + r0b * 64);
    gl16(Bb + ga + 64, (char*)Bs + 8192 + r0a * 64);
    gl16(Bb + gb + 64, (char*)Bs + 8192 + r0b * 64);

    for (int tt = 0; tt < 32; ++tt) {
        if (tt < 31) {
            asm volatile("s_waitcnt vmcnt(4)" ::: "memory");
        } else {
            asm volatile("s_waitcnt vmcnt(0)" ::: "memory");
        }
        __builtin_amdgcn_s_barrier();
        __builtin_amdgcn_sched_barrier(0);
        if (tt < 30) {   // stage K-step t+2 into buffer (t+2)%3
            const int nb = (tt + 2) % 3;
            const size_t ko = (size_t)(tt + 2) * 64;   // 32 elems * 2B
            char* Asn = (char*)As + nb * 8192;
            char* Bsn = (char*)Bs + nb * 8192;
            gl16(Ab + ga + ko, Asn + r0a * 64);
            gl16(Ab + gb + ko, Asn + r0b * 64);
            gl16(Bb + ga + ko, Bsn + r0a * 64);
            gl16(Bb + gb + ko, Bsn + r0b * 64);
        }
        const char* AsB = (const char*)As + (tt % 3) * 8192;
        const char* BsB = (const char*)Bs + (tt % 3) * 8192;
        bf16x8 af[4], bfr[4];
#pragma unroll
        for (int m = 0; m < 4; ++m)
            af[m] = *(const bf16x8*)(AsB + (wr * 64 + m * 16 + lr) * 64 + lg * 16);
#pragma unroll
        for (int n = 0; n < 4; ++n)
            bfr[n] = *(const bf16x8*)(BsB + (wc * 64 + n * 16 + lr) * 64 + lg * 16);
#pragma unroll
        for (int m = 0; m < 4; ++m)
#pragma unroll
            for (int n = 0; n < 4; ++n)
                acc[m][n] = __builtin_amdgcn_mfma_f32_16x16x32_bf16(af[m], bfr[n],
                                                                    acc[m][n], 0, 0, 0);
    }

    const float QSCALE = 0.125f * 1.44269504f;
#pragma unroll
    for (int n = 0; n < 4; ++n) {
        const int col = bcol + wc * 64 + n * 16 + lr;
        if (MODE == 0) {
#pragma unroll
            for (int m = 0; m < 4; ++m)
#pragma unroll
                for (int r = 0; r < 4; ++r) {
                    int row = brow + wr * 64 + m * 16 + 4 * lg + r;
                    int b = row >> 11, l = row & 2047;
                    float val = acc[m][n][r];
                    if (col < 1024) {
                        int hh = col >> 6, d = col & 63;
                        oq[(((size_t)b * 16 + hh) * 2048 + l) * 64 + d] =
                            f2bf((val + bias0[col]) * QSCALE);
                    } else if (col < 2048) {
                        int c = col - 1024, hh = c >> 6, d = c & 63;
                        ok_[(((size_t)b * 16 + hh) * 2048 + l) * 64 + d] =
                            f2bf(val + bias1[c]);
                    } else {
                        int c = col - 2048, hh = c >> 6, d = c & 63;
                        ov[(((size_t)b * 16 + hh) * 64 + d) * 2048 + l] =
                            f2bf(val + bias2[c]);
                    }
                }
        } else {
            const float bb = bias0[col];
#pragma unroll
            for (int m = 0; m < 4; ++m)
#pragma unroll
                for (int r = 0; r < 4; ++r) {
                    int row = brow + wr * 64 + m * 16 + 4 * lg + r;
                    oc[(size_t)row * 1024 + col] = acc[m][n][r] + bb;
                }
        }
    }
}

// ---------------------------------------------------------------- attention
// (R8 version, verbatim — measured 69.3us. R9's direct-global variant
// regressed to 180us: scattered per-lane K/V reads are L2-latency-bound.)
// Each wave computes 32 q-rows (two 16-row sub-blocks A,B) -> every K/V
// fragment read from LDS feeds TWO MFMAs. S^T = mfma(K,Q); MAX-FREE softmax;
// PV: 16x16x16 MFMA whose B-frag layout == S^T C-layout (no P exchange).
// 3-buffer depth-2 counted-vmcnt K/V pipeline (T4). Grid 512 = 2 blocks/CU.
__global__ __launch_bounds__(256, 2) void attn_k(const u16* __restrict__ qg_,
                                                 const u16* __restrict__ kg_,
                                                 const u16* __restrict__ vg_,
                                                 u16* __restrict__ ao) {
    __shared__ __align__(16) u16 smem[24576];   // 48KB: K0|K1|K2|V0|V1|V2
    char* Kbase = (char*)smem;                  // 3 x 8KB
    char* Vbase = (char*)smem + 24576;          // 3 x 8KB
    const int t = threadIdx.x, w = t >> 6, lane = t & 63;
    const int lr = lane & 15, lg = lane >> 4;
    const int bid = blockIdx.y * 16 + blockIdx.x;
    const int qt = (bid >> 3) & 15;
    const int bh = ((bid >> 7) << 3) | (bid & 7);
    const int q0 = qt * 128, h = bh & 15, bb = bh >> 4;
    const float sl2 = exp2f(-0.5f * (float)(h + 1)) * 1.44269504f; // slope*log2e

    const int U0 = (w * 2) * 64 + lane, U1 = U0 + 64;
    const int rr0 = U0 >> 3, u0 = U0 & 7, rr1 = U1 >> 3, u1 = U1 & 7;
    const int koff0 = rr0 * 128 + ((u0 ^ (rr0 & 7)) << 4);
    const int koff1 = rr1 * 128 + ((u1 ^ (rr1 & 7)) << 4);
    const int voff0 = rr0 * 4096 + ((u0 ^ (rr0 & 7)) << 4);
    const int voff1 = rr1 * 4096 + ((u1 ^ (rr1 & 7)) << 4);
    const int lds0 = (w * 2) * 1024, lds1 = lds0 + 1024;

    const char* khead = (const char*)(kg_ + (size_t)bh * 2048 * 64);
    const char* vhead = (const char*)(vg_ + (size_t)bh * 64 * 2048);

    // Q fragments straight from global, 32 rows per wave (issued FIRST so the
    // loop's vmcnt(4) at tt=0 also covers them)
    const char* qpA = (const char*)qg_ +
                      ((size_t)bh * 2048 + q0 + w * 32 + lr) * 128;
    bf16x8 qa0A = *(const bf16x8*)(qpA + lg * 16);
    bf16x8 qa1A = *(const bf16x8*)(qpA + 64 + lg * 16);
    bf16x8 qa0B = *(const bf16x8*)(qpA + 2048 + lg * 16);
    bf16x8 qa1B = *(const bf16x8*)(qpA + 2048 + 64 + lg * 16);

    // prologue: stage tiles 0 and 1 (issue order: tile0 x4, tile1 x4)
    gl16(khead + koff0, Kbase + lds0);
    gl16(khead + koff1, Kbase + lds1);
    gl16(vhead + voff0, Vbase + lds0);
    gl16(vhead + voff1, Vbase + lds1);
    gl16(khead + 8192 + koff0, Kbase + 8192 + lds0);
    gl16(khead + 8192 + koff1, Kbase + 8192 + lds1);
    gl16(vhead + 128 + voff0, Vbase + 8192 + lds0);
    gl16(vhead + 128 + voff1, Vbase + 8192 + lds1);

    // C-init: abF2[n][r] = sl2*(jloc - 2047) - 16  (q-independent: shared A/B)
    f32x4 abF2[4];
#pragma unroll
    for (int n = 0; n < 4; ++n)
#pragma unroll
        for (int r = 0; r < 4; ++r)
            abF2[n][r] = sl2 * (float)(n * 16 + 4 * lg + r - 2047) - 16.0f;
    const float ainc = sl2 * 64.0f;
    float scalJ = 0.f;                // sl2 * j0
    f32x4 oaccA[4], oaccB[4], l4A, l4B;
#pragma unroll
    for (int nn = 0; nn < 4; ++nn) {
        oaccA[nn] = (f32x4){0.f, 0.f, 0.f, 0.f};
        oaccB[nn] = (f32x4){0.f, 0.f, 0.f, 0.f};
    }
    l4A = (f32x4){0.f, 0.f, 0.f, 0.f};
    l4B = (f32x4){0.f, 0.f, 0.f, 0.f};
#if !HAVE_MFMA16
    const int srcA = lr + ((lg & 1) << 5);
    const int srcB = srcA + 16;
    const bool hiHalf = (lg >> 1) != 0;
#endif

    for (int tt = 0; tt < 32; ++tt) {
        if (tt < 31) {
            asm volatile("s_waitcnt vmcnt(4)" ::: "memory");
        } else {
            asm volatile("s_waitcnt vmcnt(0)" ::: "memory");
        }
        __builtin_amdgcn_s_barrier();
        __builtin_amdgcn_sched_barrier(0);
        if (tt < 30) {   // stage tile t+2 into buffer (t+2)%3
            const int nb = (tt + 2) % 3;
            const char* ks = khead + (size_t)(tt + 2) * 8192;
            const char* vs = vhead + (size_t)(tt + 2) * 128;
            gl16(ks + koff0, Kbase + nb * 8192 + lds0);
            gl16(ks + koff1, Kbase + nb * 8192 + lds1);
            gl16(vs + voff0, Vbase + nb * 8192 + lds0);
            gl16(vs + voff1, Vbase + nb * 8192 + lds1);
        }
        const char* Kc = Kbase + (tt % 3) * 8192;
        const char* Vc = Vbase + (tt % 3) * 8192;

        // S^T = mfma(K, Q): each K fragment feeds BOTH q-sub-blocks
        f32x4 saA[4], saB[4];
        __builtin_amdgcn_s_setprio(1);
#pragma unroll
        for (int n = 0; n < 4; ++n) {
            bf16x8 kf = *(const bf16x8*)(Kc + (n * 16 + lr) * 128 +
                                         ((lg ^ (lr & 7)) << 4));
            saA[n] = __builtin_amdgcn_mfma_f32_16x16x32_bf16(kf, qa0A, abF2[n],
                                                             0, 0, 0);
            saB[n] = __builtin_amdgcn_mfma_f32_16x16x32_bf16(kf, qa0B, abF2[n],
                                                             0, 0, 0);
        }
#pragma unroll
        for (int n = 0; n < 4; ++n) {
            bf16x8 kf = *(const bf16x8*)(Kc + (n * 16 + lr) * 128 +
                                         (((4 + lg) ^ (lr & 7)) << 4));
            saA[n] = __builtin_amdgcn_mfma_f32_16x16x32_bf16(kf, qa1A, saA[n],
                                                             0, 0, 0);
            saB[n] = __builtin_amdgcn_mfma_f32_16x16x32_bf16(kf, qa1B, saB[n],
                                                             0, 0, 0);
        }
        __builtin_amdgcn_s_setprio(0);

        // max-free softmax: P = exp2(e' + sl2*j0); sums deferred to epilogue
#pragma unroll
        for (int n = 0; n < 4; ++n)
#pragma unroll
            for (int r = 0; r < 4; ++r) {
                saA[n][r] = exp2f(saA[n][r] + scalJ);
                saB[n][r] = exp2f(saB[n][r] + scalJ);
            }
#pragma unroll
        for (int n = 0; n < 4; ++n) { l4A += saA[n]; l4B += saB[n]; }
        scalJ += ainc;

#if HAVE_MFMA16
        // pack P (C-layout) into 16x16x16 B-frags: col=q=lr, k=4lg+e == j-layout
        s16x4 pnA[4], pnB[4];
#pragma unroll
        for (int n = 0; n < 4; ++n) {
            u32 lo, hi;
            asm("v_cvt_pk_bf16_f32 %0, %1, %2"
                : "=v"(lo) : "v"(saA[n][0]), "v"(saA[n][1]));
            asm("v_cvt_pk_bf16_f32 %0, %1, %2"
                : "=v"(hi) : "v"(saA[n][2]), "v"(saA[n][3]));
            u32x2 tmpa = {lo, hi};
            pnA[n] = __builtin_bit_cast(s16x4, tmpa);
            asm("v_cvt_pk_bf16_f32 %0, %1, %2"
                : "=v"(lo) : "v"(saB[n][0]), "v"(saB[n][1]));
            asm("v_cvt_pk_bf16_f32 %0, %1, %2"
                : "=v"(hi) : "v"(saB[n][2]), "v"(saB[n][3]));
            u32x2 tmpb = {lo, hi};
            pnB[n] = __builtin_bit_cast(s16x4, tmpb);
        }
        // O^T += V^T * P: each V fragment feeds BOTH q-sub-blocks
        __builtin_amdgcn_s_setprio(1);
#pragma unroll
        for (int n = 0; n < 4; ++n)
#pragma unroll
            for (int nn = 0; nn < 4; ++nn) {
                s16x4 va = *(const s16x4*)(Vc + (nn * 16 + lr) * 128 +
                                           (((2 * n + (lg >> 1)) ^ (lr & 7)) << 4) +
                                           ((lg & 1) << 3));
                oaccA[nn] = __builtin_amdgcn_mfma_f32_16x16x16bf16_1k(va, pnA[n],
                                                                      oaccA[nn],
                                                                      0, 0, 0);
                oaccB[nn] = __builtin_amdgcn_mfma_f32_16x16x16bf16_1k(va, pnB[n],
                                                                      oaccB[nn],
                                                                      0, 0, 0);
            }
        __builtin_amdgcn_s_setprio(0);
#else
        // fallback: exchange to 16x16x32 B-frag layout (R4-proven path), A then B
        u32 pk[8];
        u32x4 pb0, pb1;
#pragma unroll
        for (int n = 0; n < 4; ++n)
#pragma unroll
            for (int rp = 0; rp < 2; ++rp) {
                u32 rpk;
                asm("v_cvt_pk_bf16_f32 %0, %1, %2"
                    : "=v"(rpk) : "v"(saA[n][2 * rp]), "v"(saA[n][2 * rp + 1]));
                pk[n * 2 + rp] = rpk;
            }
#pragma unroll
        for (int g = 0; g < 4; ++g) {
            int src = (g < 2) ? srcA : srcB;
            u32 a0 = (u32)__shfl((int)pk[0 + (g & 1)], src);
            u32 a1 = (u32)__shfl((int)pk[2 + (g & 1)], src);
            u32 b0 = (u32)__shfl((int)pk[4 + (g & 1)], src);
            u32 b1 = (u32)__shfl((int)pk[6 + (g & 1)], src);
            pb0[g] = hiHalf ? a1 : a0;
            pb1[g] = hiHalf ? b1 : b0;
        }
        {
            bf16x8 pf0 = __builtin_bit_cast(bf16x8, pb0);
            bf16x8 pf1 = __builtin_bit_cast(bf16x8, pb1);
#pragma unroll
            for (int nn = 0; nn < 4; ++nn) {
                bf16x8 vf0 = *(const bf16x8*)(Vc + (nn * 16 + lr) * 128 +
                                              ((lg ^ (lr & 7)) << 4));
                oaccA[nn] = __builtin_amdgcn_mfma_f32_16x16x32_bf16(vf0, pf0,
                                                                    oaccA[nn], 0, 0, 0);
                bf16x8 vf1 = *(const bf16x8*)(Vc + (nn * 16 + lr) * 128 +
                                              (((4 + lg) ^ (lr & 7)) << 4));
                oaccA[nn] = __builtin_amdgcn_mfma_f32_16x16x32_bf16(vf1, pf1,
                                                                    oaccA[nn], 0, 0, 0);
            }
        }
#pragma unroll
        for (int n = 0; n < 4; ++n)
#pragma unroll
            for (int rp = 0; rp < 2; ++rp) {
                u32 rpk;
                asm("v_cvt_pk_bf16_f32 %0, %1, %2"
                    : "=v"(rpk) : "v"(saB[n][2 * rp]), "v"(saB[n][2 * rp + 1]));
                pk[n * 2 + rp] = rpk;
            }
#pragma unroll
        for (int g = 0; g < 4; ++g) {
            int src = (g < 2) ? srcA : srcB;
            u32 a0 = (u32)__shfl((int)pk[0 + (g & 1)], src);
            u32 a1 = (u32)__shfl((int)pk[2 + (g & 1)], src);
            u32 b0 = (u32)__shfl((int)pk[4 + (g & 1)], src);
            u32 b1 = (u32)__shfl((int)pk[6 + (g & 1)], src);
            pb0[g] = hiHalf ? a1 : a0;
            pb1[g] = hiHalf ? b1 : b0;
        }
        {
            bf16x8 pf0 = __builtin_bit_cast(bf16x8, pb0);
            bf16x8 pf1 = __builtin_bit_cast(bf16x8, pb1);
#pragma unroll
            for (int nn = 0; nn < 4; ++nn) {
                bf16x8 vf0 = *(const bf16x8*)(Vc + (nn * 16 + lr) * 128 +
                                              ((lg ^ (lr & 7)) << 4));
                oaccB[nn] = __builtin_amdgcn_mfma_f32_16x16x32_bf16(vf0, pf0,
                                                                    oaccB[nn], 0, 0, 0);
                bf16x8 vf1 = *(const bf16x8*)(Vc + (nn * 16 + lr) * 128 +
                                              (((4 + lg) ^ (lr & 7)) << 4));
                oaccB[nn] = __builtin_amdgcn_mfma_f32_16x16x32_bf16(vf1, pf1,
                                                                    oaccB[nn], 0, 0, 0);
            }
        }
#endif
    }

    // epilogue: l reductions, normalize, transpose O^T -> O via per-wave LDS
    // scratch (32 rows x 72 u16 per wave = 4.5KB; disjoint A/B halves).
    __syncthreads();   // all waves done reading K/V buffers
    float lA = (l4A[0] + l4A[1]) + (l4A[2] + l4A[3]);
    lA += __shfl_xor(lA, 16);
    lA += __shfl_xor(lA, 32);
    float lB = (l4B[0] + l4B[1]) + (l4B[2] + l4B[3]);
    lB += __shfl_xor(lB, 16);
    lB += __shfl_xor(lB, 32);
    const float linvA = 1.0f / lA, linvB = 1.0f / lB;
    u16* ow = smem + w * (32 * 72);
#pragma unroll
    for (int nn = 0; nn < 4; ++nn)
#pragma unroll
        for (int r = 0; r < 4; ++r) {
            ow[lr * 72 + nn * 16 + 4 * lg + r] = f2bf(oaccA[nn][r] * linvA);
            ow[(16 + lr) * 72 + nn * 16 + 4 * lg + r] = f2bf(oaccB[nn][r] * linvB);
        }
    __syncthreads();
    const int q_ = lane >> 2, d0 = (lane & 3) << 4;
    const u16* orowA = smem + w * (32 * 72) + q_ * 72 + d0;
    const u16* orowB = orowA + 16 * 72;
    u16x8 a0 = *(const u16x8*)(orowA);
    u16x8 a1 = *(const u16x8*)(orowA + 8);
    u16x8 b0 = *(const u16x8*)(orowB);
    u16x8 b1 = *(const u16x8*)(orowB + 8);
    size_t gaddr = ((size_t)bb * 2048 + q0 + w * 32 + q_) * 1024 + h * 64 + d0;
    *(u16x8*)(ao + gaddr) = a0;
    *(u16x8*)(ao + gaddr + 8) = a1;
    *(u16x8*)(ao + gaddr + 16 * 1024) = b0;
    *(u16x8*)(ao + gaddr + 16 * 1024 + 8) = b1;
}

// ---------------------------------------------------------------- launch
extern "C" void kernel_launch(void* const* d_in, const int* in_sizes, int n_in,
                              void* d_out, int out_size, void* d_ws, size_t ws_size,
                              hipStream_t stream) {
    const float* x  = (const float*)d_in[0];
    const float* Wq = (const float*)d_in[1];
    const float* bq = (const float*)d_in[2];
    const float* Wk = (const float*)d_in[3];
    const float* bk = (const float*)d_in[4];
    const float* Wv = (const float*)d_in[5];
    const float* bv = (const float*)d_in[6];
    const float* Wo = (const float*)d_in[7];
    const float* bo = (const float*)d_in[8];

    const size_t MB = 1u << 20;
    if (ws_size < 40 * MB) return;
    char* ws = (char*)d_ws;
    u16* xb    = (u16*)(ws);             // 8MB  [4096][1024] bf16 (reused as ao)
    u16* wqkvt = (u16*)(ws + 8 * MB);    // 6MB  [3072][1024] = [Wq^T;Wk^T;Wv^T]
    u16* wot   = (u16*)(ws + 14 * MB);   // 2MB  Wo^T
    u16* qb    = (u16*)(ws + 16 * MB);   // 8MB  [32][2048][64]
    u16* kb    = (u16*)(ws + 24 * MB);   // 8MB  [32][2048][64]
    u16* vt    = (u16*)(ws + 32 * MB);   // 8MB  [32][64][2048]
    u16* ao    = xb;

    cvt_x_k<<<2048, 256, 0, stream>>>(x, xb);
    cvt_wT4_k<<<dim3(16, 16, 4), 256, 0, stream>>>(Wq, Wk, Wv, Wo, wqkvt, wot);

    gemm_k<0><<<dim3(32, 24), 256, 0, stream>>>(xb, wqkvt, bq, bk, bv,
                                                qb, kb, vt, nullptr);
    attn_k<<<dim3(16, 32), 256, 0, stream>>>(qb, kb, vt, ao);
    gemm_k<1><<<dim3(32, 8), 256, 0, stream>>>(ao, wot, bo, nullptr, nullptr,
                                               nullptr, nullptr, nullptr,
                                               (float*)d_out);
}

// Round 11
// 143.559 us; speedup vs baseline: 1.8155x; 1.0053x over previous
//
#include <hip/hip_runtime.h>
#include <cstdint>
#include <cstddef>

typedef unsigned short u16;
typedef unsigned int u32;
typedef __bf16 bf16x8 __attribute__((ext_vector_type(8)));
typedef float f32x4 __attribute__((ext_vector_type(4)));
typedef u32 u32x4 __attribute__((ext_vector_type(4)));
typedef u32 u32x2 __attribute__((ext_vector_type(2)));
typedef unsigned short u16x8 __attribute__((ext_vector_type(8)));
typedef short s16x4 __attribute__((ext_vector_type(4)));

#if __has_builtin(__builtin_amdgcn_mfma_f32_16x16x16bf16_1k)
#define HAVE_MFMA16 1
#else
#define HAVE_MFMA16 0
#endif

// f32 -> bf16 round-to-nearest-even (finite inputs only)
__device__ __forceinline__ u16 f2bf(float f) {
    u32 u = __float_as_uint(f);
    u += 0x7fffu + ((u >> 16) & 1u);
    return (u16)(u >> 16);
}

// async global->LDS, 16B per lane. LDS ptr must be wave-uniform; HW adds lane*16.
__device__ __forceinline__ void gl16(const void* g, void* l) {
    __builtin_amdgcn_global_load_lds(
        (const __attribute__((address_space(1))) unsigned int*)g,
        (__attribute__((address_space(3))) unsigned int*)l, 16, 0, 0);
}

// ---------------------------------------------------------------- conversions
__global__ __launch_bounds__(256) void cvt_x_k(const float* __restrict__ x,
                                               u16* __restrict__ o) {
    int i = blockIdx.x * 256 + threadIdx.x;
    const float4* xv = (const float4*)x;
    float4 a = xv[2 * i], b = xv[2 * i + 1];
    ushort4 r0, r1;
    r0.x = f2bf(a.x); r0.y = f2bf(a.y); r0.z = f2bf(a.z); r0.w = f2bf(a.w);
    r1.x = f2bf(b.x); r1.y = f2bf(b.y); r1.z = f2bf(b.z); r1.w = f2bf(b.w);
    ((ushort4*)o)[2 * i] = r0;
    ((ushort4*)o)[2 * i + 1] = r1;
}

// All four W [1024][1024] f32 (k,n) -> bf16 (n,k) transposes in ONE launch.
// blockIdx.z selects {Wq,Wk,Wv,Wo}.
__global__ __launch_bounds__(256) void cvt_wT4_k(const float* __restrict__ Wq,
                                                 const float* __restrict__ Wk,
                                                 const float* __restrict__ Wv,
                                                 const float* __restrict__ Wo,
                                                 u16* __restrict__ oqkv,
                                                 u16* __restrict__ oo) {
    __shared__ float tile[64][65];
    const int z = blockIdx.z;
    const float* W = (z == 0) ? Wq : (z == 1) ? Wk : (z == 2) ? Wv : Wo;
    u16* o = (z < 3) ? (oqkv + ((size_t)z << 20)) : oo;
    const int bx = blockIdx.x, by = blockIdx.y;
    const int t = threadIdx.x, tn = t & 63, tr = t >> 6;
#pragma unroll
    for (int r = 0; r < 16; ++r) {
        int kk = r * 4 + tr;
        tile[kk][tn] = W[(size_t)(by * 64 + kk) * 1024 + bx * 64 + tn];
    }
    __syncthreads();
#pragma unroll
    for (int r = 0; r < 16; ++r) {
        int nn = r * 4 + tr;
        o[(size_t)(bx * 64 + nn) * 1024 + by * 64 + tn] = f2bf(tile[tn][nn]);
    }
}

// ---------------------------------------------------------------- GEMM 128x128
// A [M][1024] bf16 row-major, Bt [N][1024] bf16 (= B^T), K=1024.
// 3-buffer depth-2 counted-vmcnt pipeline (T4):
//   iter t: vmcnt(4); barrier; stage(t+2); compute(t)
// MODE 0: fused QKV epilogue -> q (pre-scaled by 0.125*log2e), k as
//         [BH][2048][64], v transposed [BH][64][2048]
// MODE 1: f32 out [M][1024] + bias
template <int MODE>
__global__ __launch_bounds__(256) void gemm_k(
    const u16* __restrict__ A, const u16* __restrict__ Bt,
    const float* __restrict__ bias0, const float* __restrict__ bias1,
    const float* __restrict__ bias2,
    u16* __restrict__ oq, u16* __restrict__ ok_, u16* __restrict__ ov,
    float* __restrict__ oc) {
    __shared__ __align__(16) u16 As[3 * 128 * 32];   // 24KB
    __shared__ __align__(16) u16 Bs[3 * 128 * 32];   // 24KB
    const int t = threadIdx.x, w = t >> 6, lane = t & 63;
    const int lr = lane & 15, lg = lane >> 4;
    const int brow = blockIdx.x * 128, bcol = blockIdx.y * 128;
    const int wr = w >> 1, wc = w & 1;
    const char* Ab = (const char*)A + (size_t)brow * 2048;
    const char* Bb = (const char*)Bt + (size_t)bcol * 2048;
    const int lrow = lane >> 2, lcol = (lane & 3) << 4;
    // per-wave staging rows (16 rows x 64B per gl16 instruction)
    const int r0a = w * 32, r0b = w * 32 + 16;
    const size_t ga = (size_t)(r0a + lrow) * 2048 + lcol;
    const size_t gb = (size_t)(r0b + lrow) * 2048 + lcol;

    f32x4 acc[4][4];
#pragma unroll
    for (int m = 0; m < 4; ++m)
#pragma unroll
        for (int n = 0; n < 4; ++n) acc[m][n] = (f32x4){0.f, 0.f, 0.f, 0.f};

    // prologue: stage K-steps 0 and 1 into buffers 0,1 (issue order matters)
    gl16(Ab + ga, (char*)As + r0a * 64);
    gl16(Ab + gb, (char*)As + r0b * 64);
    gl16(Bb + ga, (char*)Bs + r0a * 64);
    gl16(Bb + gb, (char*)Bs + r0b * 64);
    gl16(Ab + ga + 64, (char*)As + 8192 + r0a * 64);
    gl16(Ab + gb + 64, (char*)As + 8192 + r0b * 64);
    gl16(Bb + ga + 64, (char*)Bs + 8192 + r0a * 64);
    gl16(Bb + gb + 64, (char*)Bs + 8192 + r0b * 64);

    for (int tt = 0; tt < 32; ++tt) {
        if (tt < 31) {
            asm volatile("s_waitcnt vmcnt(4)" ::: "memory");
        } else {
            asm volatile("s_waitcnt vmcnt(0)" ::: "memory");
        }
        __builtin_amdgcn_s_barrier();
        __builtin_amdgcn_sched_barrier(0);
        if (tt < 30) {   // stage K-step t+2 into buffer (t+2)%3
            const int nb = (tt + 2) % 3;
            const size_t ko = (size_t)(tt + 2) * 64;   // 32 elems * 2B
            char* Asn = (char*)As + nb * 8192;
            char* Bsn = (char*)Bs + nb * 8192;
            gl16(Ab + ga + ko, Asn + r0a * 64);
            gl16(Ab + gb + ko, Asn + r0b * 64);
            gl16(Bb + ga + ko, Bsn + r0a * 64);
            gl16(Bb + gb + ko, Bsn + r0b * 64);
        }
        const char* AsB = (const char*)As + (tt % 3) * 8192;
        const char* BsB = (const char*)Bs + (tt % 3) * 8192;
        bf16x8 af[4], bfr[4];
#pragma unroll
        for (int m = 0; m < 4; ++m)
            af[m] = *(const bf16x8*)(AsB + (wr * 64 + m * 16 + lr) * 64 + lg * 16);
#pragma unroll
        for (int n = 0; n < 4; ++n)
            bfr[n] = *(const bf16x8*)(BsB + (wc * 64 + n * 16 + lr) * 64 + lg * 16);
#pragma unroll
        for (int m = 0; m < 4; ++m)
#pragma unroll
            for (int n = 0; n < 4; ++n)
                acc[m][n] = __builtin_amdgcn_mfma_f32_16x16x32_bf16(af[m], bfr[n],
                                                                    acc[m][n], 0, 0, 0);
    }

    const float QSCALE = 0.125f * 1.44269504f;
#pragma unroll
    for (int n = 0; n < 4; ++n) {
        const int col = bcol + wc * 64 + n * 16 + lr;
        if (MODE == 0) {
#pragma unroll
            for (int m = 0; m < 4; ++m)
#pragma unroll
                for (int r = 0; r < 4; ++r) {
                    int row = brow + wr * 64 + m * 16 + 4 * lg + r;
                    int b = row >> 11, l = row & 2047;
                    float val = acc[m][n][r];
                    if (col < 1024) {
                        int hh = col >> 6, d = col & 63;
                        oq[(((size_t)b * 16 + hh) * 2048 + l) * 64 + d] =
                            f2bf((val + bias0[col]) * QSCALE);
                    } else if (col < 2048) {
                        int c = col - 1024, hh = c >> 6, d = c & 63;
                        ok_[(((size_t)b * 16 + hh) * 2048 + l) * 64 + d] =
                            f2bf(val + bias1[c]);
                    } else {
                        int c = col - 2048, hh = c >> 6, d = c & 63;
                        ov[(((size_t)b * 16 + hh) * 64 + d) * 2048 + l] =
                            f2bf(val + bias2[c]);
                    }
                }
        } else {
            const float bb = bias0[col];
#pragma unroll
            for (int m = 0; m < 4; ++m)
#pragma unroll
                for (int r = 0; r < 4; ++r) {
                    int row = brow + wr * 64 + m * 16 + 4 * lg + r;
                    oc[(size_t)row * 1024 + col] = acc[m][n][r] + bb;
                }
        }
    }
}

// ---------------------------------------------------------------- attention
// R8 skeleton (3-buffer depth-2 counted-vmcnt, 32-row waves, grid 512) with:
//  - V b64 reads hoisted BEFORE softmax (latency hidden under QK+exp chain)
//  - scalJ folded into C-init (abF2 += ainc per tile; exp2 takes sa directly)
//  - l computed via MFMA(A=ones, P) -> kills 32 VALU adds/iter + epilogue
//    shuffles; MFMA reduces across lg groups itself. l is bf16-P-consistent.
__global__ __launch_bounds__(256, 2) void attn_k(const u16* __restrict__ qg_,
                                                 const u16* __restrict__ kg_,
                                                 const u16* __restrict__ vg_,
                                                 u16* __restrict__ ao) {
    __shared__ __align__(16) u16 smem[24576];   // 48KB: K0|K1|K2|V0|V1|V2
    char* Kbase = (char*)smem;                  // 3 x 8KB
    char* Vbase = (char*)smem + 24576;          // 3 x 8KB
    const int t = threadIdx.x, w = t >> 6, lane = t & 63;
    const int lr = lane & 15, lg = lane >> 4;
    const int bid = blockIdx.y * 16 + blockIdx.x;
    const int qt = (bid >> 3) & 15;
    const int bh = ((bid >> 7) << 3) | (bid & 7);
    const int q0 = qt * 128, h = bh & 15, bb = bh >> 4;
    const float sl2 = exp2f(-0.5f * (float)(h + 1)) * 1.44269504f; // slope*log2e

    const int U0 = (w * 2) * 64 + lane, U1 = U0 + 64;
    const int rr0 = U0 >> 3, u0 = U0 & 7, rr1 = U1 >> 3, u1 = U1 & 7;
    const int koff0 = rr0 * 128 + ((u0 ^ (rr0 & 7)) << 4);
    const int koff1 = rr1 * 128 + ((u1 ^ (rr1 & 7)) << 4);
    const int voff0 = rr0 * 4096 + ((u0 ^ (rr0 & 7)) << 4);
    const int voff1 = rr1 * 4096 + ((u1 ^ (rr1 & 7)) << 4);
    const int lds0 = (w * 2) * 1024, lds1 = lds0 + 1024;

    const char* khead = (const char*)(kg_ + (size_t)bh * 2048 * 64);
    const char* vhead = (const char*)(vg_ + (size_t)bh * 64 * 2048);

    // Q fragments straight from global, 32 rows per wave (issued FIRST so the
    // loop's vmcnt(4) at tt=0 also covers them)
    const char* qpA = (const char*)qg_ +
                      ((size_t)bh * 2048 + q0 + w * 32 + lr) * 128;
    bf16x8 qa0A = *(const bf16x8*)(qpA + lg * 16);
    bf16x8 qa1A = *(const bf16x8*)(qpA + 64 + lg * 16);
    bf16x8 qa0B = *(const bf16x8*)(qpA + 2048 + lg * 16);
    bf16x8 qa1B = *(const bf16x8*)(qpA + 2048 + 64 + lg * 16);

    // prologue: stage tiles 0 and 1 (issue order: tile0 x4, tile1 x4)
    gl16(khead + koff0, Kbase + lds0);
    gl16(khead + koff1, Kbase + lds1);
    gl16(vhead + voff0, Vbase + lds0);
    gl16(vhead + voff1, Vbase + lds1);
    gl16(khead + 8192 + koff0, Kbase + 8192 + lds0);
    gl16(khead + 8192 + koff1, Kbase + 8192 + lds1);
    gl16(vhead + 128 + voff0, Vbase + 8192 + lds0);
    gl16(vhead + 128 + voff1, Vbase + 8192 + lds1);

    // C-init carries the whole exponent shift; advanced by ainc per tile.
    f32x4 abF2[4];
#pragma unroll
    for (int n = 0; n < 4; ++n)
#pragma unroll
        for (int r = 0; r < 4; ++r)
            abF2[n][r] = sl2 * (float)(n * 16 + 4 * lg + r - 2047) - 16.0f;
    const float ainc = sl2 * 64.0f;
    f32x4 oaccA[4], oaccB[4];
#pragma unroll
    for (int nn = 0; nn < 4; ++nn) {
        oaccA[nn] = (f32x4){0.f, 0.f, 0.f, 0.f};
        oaccB[nn] = (f32x4){0.f, 0.f, 0.f, 0.f};
    }
#if HAVE_MFMA16
    f32x4 laccA = (f32x4){0.f, 0.f, 0.f, 0.f};
    f32x4 laccB = (f32x4){0.f, 0.f, 0.f, 0.f};
    const u32x2 onesb = {0x3F803F80u, 0x3F803F80u};   // 4 x bf16 1.0
    const s16x4 ones = __builtin_bit_cast(s16x4, onesb);
#else
    f32x4 l4A = (f32x4){0.f, 0.f, 0.f, 0.f};
    f32x4 l4B = (f32x4){0.f, 0.f, 0.f, 0.f};
    const int srcA = lr + ((lg & 1) << 5);
    const int srcB = srcA + 16;
    const bool hiHalf = (lg >> 1) != 0;
#endif

    for (int tt = 0; tt < 32; ++tt) {
        if (tt < 31) {
            asm volatile("s_waitcnt vmcnt(4)" ::: "memory");
        } else {
            asm volatile("s_waitcnt vmcnt(0)" ::: "memory");
        }
        __builtin_amdgcn_s_barrier();
        __builtin_amdgcn_sched_barrier(0);
        if (tt < 30) {   // stage tile t+2 into buffer (t+2)%3
            const int nb = (tt + 2) % 3;
            const char* ks = khead + (size_t)(tt + 2) * 8192;
            const char* vs = vhead + (size_t)(tt + 2) * 128;
            gl16(ks + koff0, Kbase + nb * 8192 + lds0);
            gl16(ks + koff1, Kbase + nb * 8192 + lds1);
            gl16(vs + voff0, Vbase + nb * 8192 + lds0);
            gl16(vs + voff1, Vbase + nb * 8192 + lds1);
        }
        const char* Kc = Kbase + (tt % 3) * 8192;
        const char* Vc = Vbase + (tt % 3) * 8192;

        // K fragment reads (8 x b128), then V reads (16 x b64) HOISTED so
        // they complete under the QK MFMAs + softmax chain.
        bf16x8 kf0[4], kf1[4];
#pragma unroll
        for (int n = 0; n < 4; ++n)
            kf0[n] = *(const bf16x8*)(Kc + (n * 16 + lr) * 128 +
                                      ((lg ^ (lr & 7)) << 4));
#pragma unroll
        for (int n = 0; n < 4; ++n)
            kf1[n] = *(const bf16x8*)(Kc + (n * 16 + lr) * 128 +
                                      (((4 + lg) ^ (lr & 7)) << 4));
#if HAVE_MFMA16
        s16x4 va_[4][4];
#pragma unroll
        for (int n = 0; n < 4; ++n)
#pragma unroll
            for (int nn = 0; nn < 4; ++nn)
                va_[n][nn] = *(const s16x4*)(Vc + (nn * 16 + lr) * 128 +
                                             (((2 * n + (lg >> 1)) ^ (lr & 7)) << 4) +
                                             ((lg & 1) << 3));
#endif

        // S^T = mfma(K, Q): each K fragment feeds BOTH q-sub-blocks
        f32x4 saA[4], saB[4];
        __builtin_amdgcn_s_setprio(1);
#pragma unroll
        for (int n = 0; n < 4; ++n) {
            saA[n] = __builtin_amdgcn_mfma_f32_16x16x32_bf16(kf0[n], qa0A, abF2[n],
                                                             0, 0, 0);
            saB[n] = __builtin_amdgcn_mfma_f32_16x16x32_bf16(kf0[n], qa0B, abF2[n],
                                                             0, 0, 0);
        }
#pragma unroll
        for (int n = 0; n < 4; ++n) {
            saA[n] = __builtin_amdgcn_mfma_f32_16x16x32_bf16(kf1[n], qa1A, saA[n],
                                                             0, 0, 0);
            saB[n] = __builtin_amdgcn_mfma_f32_16x16x32_bf16(kf1[n], qa1B, saB[n],
                                                             0, 0, 0);
        }
        __builtin_amdgcn_s_setprio(0);

        // max-free softmax: P = exp2(sa) directly (shift lives in abF2)
#pragma unroll
        for (int n = 0; n < 4; ++n)
#pragma unroll
            for (int r = 0; r < 4; ++r) {
                saA[n][r] = exp2f(saA[n][r]);
                saB[n][r] = exp2f(saB[n][r]);
            }
#pragma unroll
        for (int n = 0; n < 4; ++n) abF2[n] += ainc;

#if HAVE_MFMA16
        // pack P (C-layout) into 16x16x16 B-frags: col=q=lr, k=4lg+e == j-layout
        s16x4 pnA[4], pnB[4];
#pragma unroll
        for (int n = 0; n < 4; ++n) {
            u32 lo, hi;
            asm("v_cvt_pk_bf16_f32 %0, %1, %2"
                : "=v"(lo) : "v"(saA[n][0]), "v"(saA[n][1]));
            asm("v_cvt_pk_bf16_f32 %0, %1, %2"
                : "=v"(hi) : "v"(saA[n][2]), "v"(saA[n][3]));
            u32x2 tmpa = {lo, hi};
            pnA[n] = __builtin_bit_cast(s16x4, tmpa);
            asm("v_cvt_pk_bf16_f32 %0, %1, %2"
                : "=v"(lo) : "v"(saB[n][0]), "v"(saB[n][1]));
            asm("v_cvt_pk_bf16_f32 %0, %1, %2"
                : "=v"(hi) : "v"(saB[n][2]), "v"(saB[n][3]));
            u32x2 tmpb = {lo, hi};
            pnB[n] = __builtin_bit_cast(s16x4, tmpb);
        }
        // O^T += V^T * P ; l += ones^T * P (MFMA does the lg-group reduce)
        __builtin_amdgcn_s_setprio(1);
#pragma unroll
        for (int n = 0; n < 4; ++n) {
            laccA = __builtin_amdgcn_mfma_f32_16x16x16bf16_1k(ones, pnA[n],
                                                              laccA, 0, 0, 0);
            laccB = __builtin_amdgcn_mfma_f32_16x16x16bf16_1k(ones, pnB[n],
                                                              laccB, 0, 0, 0);
#pragma unroll
            for (int nn = 0; nn < 4; ++nn) {
                oaccA[nn] = __builtin_amdgcn_mfma_f32_16x16x16bf16_1k(va_[n][nn],
                                                                      pnA[n],
                                                                      oaccA[nn],
                                                                      0, 0, 0);
                oaccB[nn] = __builtin_amdgcn_mfma_f32_16x16x16bf16_1k(va_[n][nn],
                                                                      pnB[n],
                                                                      oaccB[nn],
                                                                      0, 0, 0);
            }
        }
        __builtin_amdgcn_s_setprio(0);
#else
        // fallback: exchange to 16x16x32 B-frag layout (R4-proven path), A then B
#pragma unroll
        for (int n = 0; n < 4; ++n) { l4A += saA[n]; l4B += saB[n]; }
        u32 pk[8];
        u32x4 pb0, pb1;
#pragma unroll
        for (int n = 0; n < 4; ++n)
#pragma unroll
            for (int rp = 0; rp < 2; ++rp) {
                u32 rpk;
                asm("v_cvt_pk_bf16_f32 %0, %1, %2"
                    : "=v"(rpk) : "v"(saA[n][2 * rp]), "v"(saA[n][2 * rp + 1]));
                pk[n * 2 + rp] = rpk;
            }
#pragma unroll
        for (int g = 0; g < 4; ++g) {
            int src = (g < 2) ? srcA : srcB;
            u32 a0 = (u32)__shfl((int)pk[0 + (g & 1)], src);
            u32 a1 = (u32)__shfl((int)pk[2 + (g & 1)], src);
            u32 b0 = (u32)__shfl((int)pk[4 + (g & 1)], src);
            u32 b1 = (u32)__shfl((int)pk[6 + (g & 1)], src);
            pb0[g] = hiHalf ? a1 : a0;
            pb1[g] = hiHalf ? b1 : b0;
        }
        {
            bf16x8 pf0 = __builtin_bit_cast(bf16x8, pb0);
            bf16x8 pf1 = __builtin_bit_cast(bf16x8, pb1);
#pragma unroll
            for (int nn = 0; nn < 4; ++nn) {
                bf16x8 vf0 = *(const bf16x8*)(Vc + (nn * 16 + lr) * 128 +
                                              ((lg ^ (lr & 7)) << 4));
                oaccA[nn] = __builtin_amdgcn_mfma_f32_16x16x32_bf16(vf0, pf0,
                                                                    oaccA[nn], 0, 0, 0);
                bf16x8 vf1 = *(const bf16x8*)(Vc + (nn * 16 + lr) * 128 +
                                              (((4 + lg) ^ (lr & 7)) << 4));
                oaccA[nn] = __builtin_amdgcn_mfma_f32_16x16x32_bf16(vf1, pf1,
                                                                    oaccA[nn], 0, 0, 0);
            }
        }
#pragma unroll
        for (int n = 0; n < 4; ++n)
#pragma unroll
            for (int rp = 0; rp < 2; ++rp) {
                u32 rpk;
                asm("v_cvt_pk_bf16_f32 %0, %1, %2"
                    : "=v"(rpk) : "v"(saB[n][2 * rp]), "v"(saB[n][2 * rp + 1]));
                pk[n * 2 + rp] = rpk;
            }
#pragma unroll
        for (int g = 0; g < 4; ++g) {
            int src = (g < 2) ? srcA : srcB;
            u32 a0 = (u32)__shfl((int)pk[0 + (g & 1)], src);
            u32 a1 = (u32)__shfl((int)pk[2 + (g & 1)], src);
            u32 b0 = (u32)__shfl((int)pk[4 + (g & 1)], src);
            u32 b1 = (u32)__shfl((int)pk[6 + (g & 1)], src);
            pb0[g] = hiHalf ? a1 : a0;
            pb1[g] = hiHalf ? b1 : b0;
        }
        {
            bf16x8 pf0 = __builtin_bit_cast(bf16x8, pb0);
            bf16x8 pf1 = __builtin_bit_cast(bf16x8, pb1);
#pragma unroll
            for (int nn = 0; nn < 4; ++nn) {
                bf16x8 vf0 = *(const bf16x8*)(Vc + (nn * 16 + lr) * 128 +
                                              ((lg ^ (lr & 7)) << 4));
                oaccB[nn] = __builtin_amdgcn_mfma_f32_16x16x32_bf16(vf0, pf0,
                                                                    oaccB[nn], 0, 0, 0);
                bf16x8 vf1 = *(const bf16x8*)(Vc + (nn * 16 + lr) * 128 +
                                              (((4 + lg) ^ (lr & 7)) << 4));
                oaccB[nn] = __builtin_amdgcn_mfma_f32_16x16x32_bf16(vf1, pf1,
                                                                    oaccB[nn], 0, 0, 0);
            }
        }
#endif
    }

    // epilogue: normalize, transpose O^T -> O via per-wave LDS scratch
    __syncthreads();   // all waves done reading K/V buffers
#if HAVE_MFMA16
    const float linvA = 1.0f / laccA[0];
    const float linvB = 1.0f / laccB[0];
#else
    float lA = (l4A[0] + l4A[1]) + (l4A[2] + l4A[3]);
    lA += __shfl_xor(lA, 16);
    lA += __shfl_xor(lA, 32);
    float lB = (l4B[0] + l4B[1]) + (l4B[2] + l4B[3]);
    lB += __shfl_xor(lB, 16);
    lB += __shfl_xor(lB, 32);
    const float linvA = 1.0f / lA, linvB = 1.0f / lB;
#endif
    u16* ow = smem + w * (32 * 72);
#pragma unroll
    for (int nn = 0; nn < 4; ++nn)
#pragma unroll
        for (int r = 0; r < 4; ++r) {
            ow[lr * 72 + nn * 16 + 4 * lg + r] = f2bf(oaccA[nn][r] * linvA);
            ow[(16 + lr) * 72 + nn * 16 + 4 * lg + r] = f2bf(oaccB[nn][r] * linvB);
        }
    __syncthreads();
    const int q_ = lane >> 2, d0 = (lane & 3) << 4;
    const u16* orowA = smem + w * (32 * 72) + q_ * 72 + d0;
    const u16* orowB = orowA + 16 * 72;
    u16x8 a0 = *(const u16x8*)(orowA);
    u16x8 a1 = *(const u16x8*)(orowA + 8);
    u16x8 b0 = *(const u16x8*)(orowB);
    u16x8 b1 = *(const u16x8*)(orowB + 8);
    size_t gaddr = ((size_t)bb * 2048 + q0 + w * 32 + q_) * 1024 + h * 64 + d0;
    *(u16x8*)(ao + gaddr) = a0;
    *(u16x8*)(ao + gaddr + 8) = a1;
    *(u16x8*)(ao + gaddr + 16 * 1024) = b0;
    *(u16x8*)(ao + gaddr + 16 * 1024 + 8) = b1;
}

// ---------------------------------------------------------------- launch
extern "C" void kernel_launch(void* const* d_in, const int* in_sizes, int n_in,
                              void* d_out, int out_size, void* d_ws, size_t ws_size,
                              hipStream_t stream) {
    const float* x  = (const float*)d_in[0];
    const float* Wq = (const float*)d_in[1];
    const float* bq = (const float*)d_in[2];
    const float* Wk = (const float*)d_in[3];
    const float* bk = (const float*)d_in[4];
    const float* Wv = (const float*)d_in[5];
    const float* bv = (const float*)d_in[6];
    const float* Wo = (const float*)d_in[7];
    const float* bo = (const float*)d_in[8];

    const size_t MB = 1u << 20;
    if (ws_size < 40 * MB) return;
    char* ws = (char*)d_ws;
    u16* xb    = (u16*)(ws);             // 8MB  [4096][1024] bf16 (reused as ao)
    u16* wqkvt = (u16*)(ws + 8 * MB);    // 6MB  [3072][1024] = [Wq^T;Wk^T;Wv^T]
    u16* wot   = (u16*)(ws + 14 * MB);   // 2MB  Wo^T
    u16* qb    = (u16*)(ws + 16 * MB);   // 8MB  [32][2048][64]
    u16* kb    = (u16*)(ws + 24 * MB);   // 8MB  [32][2048][64]
    u16* vt    = (u16*)(ws + 32 * MB);   // 8MB  [32][64][2048]
    u16* ao    = xb;

    cvt_x_k<<<2048, 256, 0, stream>>>(x, xb);
    cvt_wT4_k<<<dim3(16, 16, 4), 256, 0, stream>>>(Wq, Wk, Wv, Wo, wqkvt, wot);

    gemm_k<0><<<dim3(32, 24), 256, 0, stream>>>(xb, wqkvt, bq, bk, bv,
                                                qb, kb, vt, nullptr);
    attn_k<<<dim3(16, 32), 256, 0, stream>>>(qb, kb, vt, ao);
    gemm_k<1><<<dim3(32, 8), 256, 0, stream>>>(ao, wot, bo, nullptr, nullptr,
                                               nullptr, nullptr, nullptr,
                                               (float*)d_out);
}

// Round 12
// 125.267 us; speedup vs baseline: 2.0806x; 1.1460x over previous
//
#include <hip/hip_runtime.h>
#include <cstdint>
#include <cstddef>

typedef unsigned short u16;
typedef unsigned int u32;
typedef __bf16 bf16x8 __attribute__((ext_vector_type(8)));
typedef float f32x4 __attribute__((ext_vector_type(4)));
typedef u32 u32x4 __attribute__((ext_vector_type(4)));
typedef u32 u32x2 __attribute__((ext_vector_type(2)));
typedef unsigned short u16x8 __attribute__((ext_vector_type(8)));
typedef short s16x4 __attribute__((ext_vector_type(4)));

#if __has_builtin(__builtin_amdgcn_mfma_f32_16x16x16bf16_1k)
#define HAVE_MFMA16 1
#else
#define HAVE_MFMA16 0
#endif

// f32 -> bf16 round-to-nearest-even (finite inputs only)
__device__ __forceinline__ u16 f2bf(float f) {
    u32 u = __float_as_uint(f);
    u += 0x7fffu + ((u >> 16) & 1u);
    return (u16)(u >> 16);
}

// raw exp2: single v_exp_f32 (no OCML lib-call guard code; denormals flush
// to 0, which is exactly right for softmax tail underflow)
__device__ __forceinline__ float fexp2(float x) {
    float r;
    asm("v_exp_f32 %0, %1" : "=v"(r) : "v"(x));
    return r;
}

// async global->LDS, 16B per lane. LDS ptr must be wave-uniform; HW adds lane*16.
__device__ __forceinline__ void gl16(const void* g, void* l) {
    __builtin_amdgcn_global_load_lds(
        (const __attribute__((address_space(1))) unsigned int*)g,
        (__attribute__((address_space(3))) unsigned int*)l, 16, 0, 0);
}

// ---------------------------------------------------------------- conversions
__global__ __launch_bounds__(256) void cvt_x_k(const float* __restrict__ x,
                                               u16* __restrict__ o) {
    int i = blockIdx.x * 256 + threadIdx.x;
    const float4* xv = (const float4*)x;
    float4 a = xv[2 * i], b = xv[2 * i + 1];
    ushort4 r0, r1;
    r0.x = f2bf(a.x); r0.y = f2bf(a.y); r0.z = f2bf(a.z); r0.w = f2bf(a.w);
    r1.x = f2bf(b.x); r1.y = f2bf(b.y); r1.z = f2bf(b.z); r1.w = f2bf(b.w);
    ((ushort4*)o)[2 * i] = r0;
    ((ushort4*)o)[2 * i + 1] = r1;
}

// All four W [1024][1024] f32 (k,n) -> bf16 (n,k) transposes in ONE launch.
// blockIdx.z selects {Wq,Wk,Wv,Wo}.
__global__ __launch_bounds__(256) void cvt_wT4_k(const float* __restrict__ Wq,
                                                 const float* __restrict__ Wk,
                                                 const float* __restrict__ Wv,
                                                 const float* __restrict__ Wo,
                                                 u16* __restrict__ oqkv,
                                                 u16* __restrict__ oo) {
    __shared__ float tile[64][65];
    const int z = blockIdx.z;
    const float* W = (z == 0) ? Wq : (z == 1) ? Wk : (z == 2) ? Wv : Wo;
    u16* o = (z < 3) ? (oqkv + ((size_t)z << 20)) : oo;
    const int bx = blockIdx.x, by = blockIdx.y;
    const int t = threadIdx.x, tn = t & 63, tr = t >> 6;
#pragma unroll
    for (int r = 0; r < 16; ++r) {
        int kk = r * 4 + tr;
        tile[kk][tn] = W[(size_t)(by * 64 + kk) * 1024 + bx * 64 + tn];
    }
    __syncthreads();
#pragma unroll
    for (int r = 0; r < 16; ++r) {
        int nn = r * 4 + tr;
        o[(size_t)(bx * 64 + nn) * 1024 + by * 64 + tn] = f2bf(tile[tn][nn]);
    }
}

// ---------------------------------------------------------------- GEMM 128x128
// A [M][1024] bf16 row-major, Bt [N][1024] bf16 (= B^T), K=1024.
// 3-buffer depth-2 counted-vmcnt pipeline (T4):
//   iter t: vmcnt(4); barrier; stage(t+2); compute(t)
// LDS bank swizzle (rule #21 both-sides): linear gl16 dest + pre-swizzled
// global source col ((lane&3)^((lane>>3)&3)) + swizzled ds_read col
// (lg^((lr>>1)&3)) -> 16-lane groups spread over all 8 granules (2-way, free)
// instead of 8-way.
// MODE 0: fused QKV epilogue -> q (pre-scaled by 0.125*log2e), k as
//         [BH][2048][64], v transposed [BH][64][2048]
// MODE 1: f32 out [M][1024] + bias
template <int MODE>
__global__ __launch_bounds__(256) void gemm_k(
    const u16* __restrict__ A, const u16* __restrict__ Bt,
    const float* __restrict__ bias0, const float* __restrict__ bias1,
    const float* __restrict__ bias2,
    u16* __restrict__ oq, u16* __restrict__ ok_, u16* __restrict__ ov,
    float* __restrict__ oc) {
    __shared__ __align__(16) u16 As[3 * 128 * 32];   // 24KB
    __shared__ __align__(16) u16 Bs[3 * 128 * 32];   // 24KB
    const int t = threadIdx.x, w = t >> 6, lane = t & 63;
    const int lr = lane & 15, lg = lane >> 4;
    const int brow = blockIdx.x * 128, bcol = blockIdx.y * 128;
    const int wr = w >> 1, wc = w & 1;
    const char* Ab = (const char*)A + (size_t)brow * 2048;
    const char* Bb = (const char*)Bt + (size_t)bcol * 2048;
    const int lrow = lane >> 2;
    // swizzled source column: LDS[row][c] will hold G[row][c ^ ((row>>1)&3)]
    const int lcol = (((lane & 3) ^ ((lane >> 3) & 3)) << 4);
    // per-wave staging rows (16 rows x 64B per gl16 instruction)
    const int r0a = w * 32, r0b = w * 32 + 16;
    const size_t ga = (size_t)(r0a + lrow) * 2048 + lcol;
    const size_t gb = (size_t)(r0b + lrow) * 2048 + lcol;
    // swizzled read column offset (row>>1)&3 == (lr>>1)&3 for our rows
    const int rsw = ((lg ^ ((lr >> 1) & 3)) << 4);

    f32x4 acc[4][4];
#pragma unroll
    for (int m = 0; m < 4; ++m)
#pragma unroll
        for (int n = 0; n < 4; ++n) acc[m][n] = (f32x4){0.f, 0.f, 0.f, 0.f};

    // prologue: stage K-steps 0 and 1 into buffers 0,1 (issue order matters)
    gl16(Ab + ga, (char*)As + r0a * 64);
    gl16(Ab + gb, (char*)As + r0b * 64);
    gl16(Bb + ga, (char*)Bs + r0a * 64);
    gl16(Bb + gb, (char*)Bs + r0b * 64);
    gl16(Ab + ga + 64, (char*)As + 8192 + r0a * 64);
    gl16(Ab + gb + 64, (char*)As + 8192 + r0b * 64);
    gl16(Bb + ga + 64, (char*)Bs + 8192 + r0a * 64);
    gl16(Bb + gb + 64, (char*)Bs + 8192 + r0b * 64);

    for (int tt = 0; tt < 32; ++tt) {
        if (tt < 31) {
            asm volatile("s_waitcnt vmcnt(4)" ::: "memory");
        } else {
            asm volatile("s_waitcnt vmcnt(0)" ::: "memory");
        }
        __builtin_amdgcn_s_barrier();
        __builtin_amdgcn_sched_barrier(0);
        if (tt < 30) {   // stage K-step t+2 into buffer (t+2)%3
            const int nb = (tt + 2) % 3;
            const size_t ko = (size_t)(tt + 2) * 64;   // 32 elems * 2B
            char* Asn = (char*)As + nb * 8192;
            char* Bsn = (char*)Bs + nb * 8192;
            gl16(Ab + ga + ko, Asn + r0a * 64);
            gl16(Ab + gb + ko, Asn + r0b * 64);
            gl16(Bb + ga + ko, Bsn + r0a * 64);
            gl16(Bb + gb + ko, Bsn + r0b * 64);
        }
        const char* AsB = (const char*)As + (tt % 3) * 8192;
        const char* BsB = (const char*)Bs + (tt % 3) * 8192;
        bf16x8 af[4], bfr[4];
#pragma unroll
        for (int m = 0; m < 4; ++m)
            af[m] = *(const bf16x8*)(AsB + (wr * 64 + m * 16 + lr) * 64 + rsw);
#pragma unroll
        for (int n = 0; n < 4; ++n)
            bfr[n] = *(const bf16x8*)(BsB + (wc * 64 + n * 16 + lr) * 64 + rsw);
#pragma unroll
        for (int m = 0; m < 4; ++m)
#pragma unroll
            for (int n = 0; n < 4; ++n)
                acc[m][n] = __builtin_amdgcn_mfma_f32_16x16x32_bf16(af[m], bfr[n],
                                                                    acc[m][n], 0, 0, 0);
    }

    const float QSCALE = 0.125f * 1.44269504f;
#pragma unroll
    for (int n = 0; n < 4; ++n) {
        const int col = bcol + wc * 64 + n * 16 + lr;
        if (MODE == 0) {
#pragma unroll
            for (int m = 0; m < 4; ++m)
#pragma unroll
                for (int r = 0; r < 4; ++r) {
                    int row = brow + wr * 64 + m * 16 + 4 * lg + r;
                    int b = row >> 11, l = row & 2047;
                    float val = acc[m][n][r];
                    if (col < 1024) {
                        int hh = col >> 6, d = col & 63;
                        oq[(((size_t)b * 16 + hh) * 2048 + l) * 64 + d] =
                            f2bf((val + bias0[col]) * QSCALE);
                    } else if (col < 2048) {
                        int c = col - 1024, hh = c >> 6, d = c & 63;
                        ok_[(((size_t)b * 16 + hh) * 2048 + l) * 64 + d] =
                            f2bf(val + bias1[c]);
                    } else {
                        int c = col - 2048, hh = c >> 6, d = c & 63;
                        ov[(((size_t)b * 16 + hh) * 64 + d) * 2048 + l] =
                            f2bf(val + bias2[c]);
                    }
                }
        } else {
            const float bb = bias0[col];
#pragma unroll
            for (int m = 0; m < 4; ++m)
#pragma unroll
                for (int r = 0; r < 4; ++r) {
                    int row = brow + wr * 64 + m * 16 + 4 * lg + r;
                    oc[(size_t)row * 1024 + col] = acc[m][n][r] + bb;
                }
        }
    }
}

// ---------------------------------------------------------------- attention
// R11 structure (3-buffer depth-2 counted-vmcnt, 32-row waves, grid 512,
// V-hoist, C-init ALiBi, l-via-MFMA) with exp2f -> raw v_exp_f32.
__global__ __launch_bounds__(256, 2) void attn_k(const u16* __restrict__ qg_,
                                                 const u16* __restrict__ kg_,
                                                 const u16* __restrict__ vg_,
                                                 u16* __restrict__ ao) {
    __shared__ __align__(16) u16 smem[24576];   // 48KB: K0|K1|K2|V0|V1|V2
    char* Kbase = (char*)smem;                  // 3 x 8KB
    char* Vbase = (char*)smem + 24576;          // 3 x 8KB
    const int t = threadIdx.x, w = t >> 6, lane = t & 63;
    const int lr = lane & 15, lg = lane >> 4;
    const int bid = blockIdx.y * 16 + blockIdx.x;
    const int qt = (bid >> 3) & 15;
    const int bh = ((bid >> 7) << 3) | (bid & 7);
    const int q0 = qt * 128, h = bh & 15, bb = bh >> 4;
    const float sl2 = exp2f(-0.5f * (float)(h + 1)) * 1.44269504f; // slope*log2e

    const int U0 = (w * 2) * 64 + lane, U1 = U0 + 64;
    const int rr0 = U0 >> 3, u0 = U0 & 7, rr1 = U1 >> 3, u1 = U1 & 7;
    const int koff0 = rr0 * 128 + ((u0 ^ (rr0 & 7)) << 4);
    const int koff1 = rr1 * 128 + ((u1 ^ (rr1 & 7)) << 4);
    const int voff0 = rr0 * 4096 + ((u0 ^ (rr0 & 7)) << 4);
    const int voff1 = rr1 * 4096 + ((u1 ^ (rr1 & 7)) << 4);
    const int lds0 = (w * 2) * 1024, lds1 = lds0 + 1024;

    const char* khead = (const char*)(kg_ + (size_t)bh * 2048 * 64);
    const char* vhead = (const char*)(vg_ + (size_t)bh * 64 * 2048);

    // Q fragments straight from global, 32 rows per wave (issued FIRST so the
    // loop's vmcnt(4) at tt=0 also covers them)
    const char* qpA = (const char*)qg_ +
                      ((size_t)bh * 2048 + q0 + w * 32 + lr) * 128;
    bf16x8 qa0A = *(const bf16x8*)(qpA + lg * 16);
    bf16x8 qa1A = *(const bf16x8*)(qpA + 64 + lg * 16);
    bf16x8 qa0B = *(const bf16x8*)(qpA + 2048 + lg * 16);
    bf16x8 qa1B = *(const bf16x8*)(qpA + 2048 + 64 + lg * 16);

    // prologue: stage tiles 0 and 1 (issue order: tile0 x4, tile1 x4)
    gl16(khead + koff0, Kbase + lds0);
    gl16(khead + koff1, Kbase + lds1);
    gl16(vhead + voff0, Vbase + lds0);
    gl16(vhead + voff1, Vbase + lds1);
    gl16(khead + 8192 + koff0, Kbase + 8192 + lds0);
    gl16(khead + 8192 + koff1, Kbase + 8192 + lds1);
    gl16(vhead + 128 + voff0, Vbase + 8192 + lds0);
    gl16(vhead + 128 + voff1, Vbase + 8192 + lds1);

    // C-init carries the whole exponent shift; advanced by ainc per tile.
    f32x4 abF2[4];
#pragma unroll
    for (int n = 0; n < 4; ++n)
#pragma unroll
        for (int r = 0; r < 4; ++r)
            abF2[n][r] = sl2 * (float)(n * 16 + 4 * lg + r - 2047) - 16.0f;
    const float ainc = sl2 * 64.0f;
    f32x4 oaccA[4], oaccB[4];
#pragma unroll
    for (int nn = 0; nn < 4; ++nn) {
        oaccA[nn] = (f32x4){0.f, 0.f, 0.f, 0.f};
        oaccB[nn] = (f32x4){0.f, 0.f, 0.f, 0.f};
    }
#if HAVE_MFMA16
    f32x4 laccA = (f32x4){0.f, 0.f, 0.f, 0.f};
    f32x4 laccB = (f32x4){0.f, 0.f, 0.f, 0.f};
    const u32x2 onesb = {0x3F803F80u, 0x3F803F80u};   // 4 x bf16 1.0
    const s16x4 ones = __builtin_bit_cast(s16x4, onesb);
#else
    f32x4 l4A = (f32x4){0.f, 0.f, 0.f, 0.f};
    f32x4 l4B = (f32x4){0.f, 0.f, 0.f, 0.f};
    const int srcA = lr + ((lg & 1) << 5);
    const int srcB = srcA + 16;
    const bool hiHalf = (lg >> 1) != 0;
#endif

    for (int tt = 0; tt < 32; ++tt) {
        if (tt < 31) {
            asm volatile("s_waitcnt vmcnt(4)" ::: "memory");
        } else {
            asm volatile("s_waitcnt vmcnt(0)" ::: "memory");
        }
        __builtin_amdgcn_s_barrier();
        __builtin_amdgcn_sched_barrier(0);
        if (tt < 30) {   // stage tile t+2 into buffer (t+2)%3
            const int nb = (tt + 2) % 3;
            const char* ks = khead + (size_t)(tt + 2) * 8192;
            const char* vs = vhead + (size_t)(tt + 2) * 128;
            gl16(ks + koff0, Kbase + nb * 8192 + lds0);
            gl16(ks + koff1, Kbase + nb * 8192 + lds1);
            gl16(vs + voff0, Vbase + nb * 8192 + lds0);
            gl16(vs + voff1, Vbase + nb * 8192 + lds1);
        }
        const char* Kc = Kbase + (tt % 3) * 8192;
        const char* Vc = Vbase + (tt % 3) * 8192;

        // K fragment reads (8 x b128), then V reads (16 x b64) HOISTED so
        // they complete under the QK MFMAs + softmax chain.
        bf16x8 kf0[4], kf1[4];
#pragma unroll
        for (int n = 0; n < 4; ++n)
            kf0[n] = *(const bf16x8*)(Kc + (n * 16 + lr) * 128 +
                                      ((lg ^ (lr & 7)) << 4));
#pragma unroll
        for (int n = 0; n < 4; ++n)
            kf1[n] = *(const bf16x8*)(Kc + (n * 16 + lr) * 128 +
                                      (((4 + lg) ^ (lr & 7)) << 4));
#if HAVE_MFMA16
        s16x4 va_[4][4];
#pragma unroll
        for (int n = 0; n < 4; ++n)
#pragma unroll
            for (int nn = 0; nn < 4; ++nn)
                va_[n][nn] = *(const s16x4*)(Vc + (nn * 16 + lr) * 128 +
                                             (((2 * n + (lg >> 1)) ^ (lr & 7)) << 4) +
                                             ((lg & 1) << 3));
#endif

        // S^T = mfma(K, Q): each K fragment feeds BOTH q-sub-blocks
        f32x4 saA[4], saB[4];
        __builtin_amdgcn_s_setprio(1);
#pragma unroll
        for (int n = 0; n < 4; ++n) {
            saA[n] = __builtin_amdgcn_mfma_f32_16x16x32_bf16(kf0[n], qa0A, abF2[n],
                                                             0, 0, 0);
            saB[n] = __builtin_amdgcn_mfma_f32_16x16x32_bf16(kf0[n], qa0B, abF2[n],
                                                             0, 0, 0);
        }
#pragma unroll
        for (int n = 0; n < 4; ++n) {
            saA[n] = __builtin_amdgcn_mfma_f32_16x16x32_bf16(kf1[n], qa1A, saA[n],
                                                             0, 0, 0);
            saB[n] = __builtin_amdgcn_mfma_f32_16x16x32_bf16(kf1[n], qa1B, saB[n],
                                                             0, 0, 0);
        }
        __builtin_amdgcn_s_setprio(0);

        // max-free softmax: P = exp2(sa) via raw v_exp_f32
#pragma unroll
        for (int n = 0; n < 4; ++n)
#pragma unroll
            for (int r = 0; r < 4; ++r) {
                saA[n][r] = fexp2(saA[n][r]);
                saB[n][r] = fexp2(saB[n][r]);
            }
#pragma unroll
        for (int n = 0; n < 4; ++n) abF2[n] += ainc;

#if HAVE_MFMA16
        // pack P (C-layout) into 16x16x16 B-frags: col=q=lr, k=4lg+e == j-layout
        s16x4 pnA[4], pnB[4];
#pragma unroll
        for (int n = 0; n < 4; ++n) {
            u32 lo, hi;
            asm("v_cvt_pk_bf16_f32 %0, %1, %2"
                : "=v"(lo) : "v"(saA[n][0]), "v"(saA[n][1]));
            asm("v_cvt_pk_bf16_f32 %0, %1, %2"
                : "=v"(hi) : "v"(saA[n][2]), "v"(saA[n][3]));
            u32x2 tmpa = {lo, hi};
            pnA[n] = __builtin_bit_cast(s16x4, tmpa);
            asm("v_cvt_pk_bf16_f32 %0, %1, %2"
                : "=v"(lo) : "v"(saB[n][0]), "v"(saB[n][1]));
            asm("v_cvt_pk_bf16_f32 %0, %1, %2"
                : "=v"(hi) : "v"(saB[n][2]), "v"(saB[n][3]));
            u32x2 tmpb = {lo, hi};
            pnB[n] = __builtin_bit_cast(s16x4, tmpb);
        }
        // O^T += V^T * P ; l += ones^T * P (MFMA does the lg-group reduce)
        __builtin_amdgcn_s_setprio(1);
#pragma unroll
        for (int n = 0; n < 4; ++n) {
            laccA = __builtin_amdgcn_mfma_f32_16x16x16bf16_1k(ones, pnA[n],
                                                              laccA, 0, 0, 0);
            laccB = __builtin_amdgcn_mfma_f32_16x16x16bf16_1k(ones, pnB[n],
                                                              laccB, 0, 0, 0);
#pragma unroll
            for (int nn = 0; nn < 4; ++nn) {
                oaccA[nn] = __builtin_amdgcn_mfma_f32_16x16x16bf16_1k(va_[n][nn],
                                                                      pnA[n],
                                                                      oaccA[nn],
                                                                      0, 0, 0);
                oaccB[nn] = __builtin_amdgcn_mfma_f32_16x16x16bf16_1k(va_[n][nn],
                                                                      pnB[n],
                                                                      oaccB[nn],
                                                                      0, 0, 0);
            }
        }
        __builtin_amdgcn_s_setprio(0);
#else
        // fallback: exchange to 16x16x32 B-frag layout (R4-proven path), A then B
#pragma unroll
        for (int n = 0; n < 4; ++n) { l4A += saA[n]; l4B += saB[n]; }
        u32 pk[8];
        u32x4 pb0, pb1;
#pragma unroll
        for (int n = 0; n < 4; ++n)
#pragma unroll
            for (int rp = 0; rp < 2; ++rp) {
                u32 rpk;
                asm("v_cvt_pk_bf16_f32 %0, %1, %2"
                    : "=v"(rpk) : "v"(saA[n][2 * rp]), "v"(saA[n][2 * rp + 1]));
                pk[n * 2 + rp] = rpk;
            }
#pragma unroll
        for (int g = 0; g < 4; ++g) {
            int src = (g < 2) ? srcA : srcB;
            u32 a0 = (u32)__shfl((int)pk[0 + (g & 1)], src);
            u32 a1 = (u32)__shfl((int)pk[2 + (g & 1)], src);
            u32 b0 = (u32)__shfl((int)pk[4 + (g & 1)], src);
            u32 b1 = (u32)__shfl((int)pk[6 + (g & 1)], src);
            pb0[g] = hiHalf ? a1 : a0;
            pb1[g] = hiHalf ? b1 : b0;
        }
        {
            bf16x8 pf0 = __builtin_bit_cast(bf16x8, pb0);
            bf16x8 pf1 = __builtin_bit_cast(bf16x8, pb1);
#pragma unroll
            for (int nn = 0; nn < 4; ++nn) {
                bf16x8 vf0 = *(const bf16x8*)(Vc + (nn * 16 + lr) * 128 +
                                              ((lg ^ (lr & 7)) << 4));
                oaccA[nn] = __builtin_amdgcn_mfma_f32_16x16x32_bf16(vf0, pf0,
                                                                    oaccA[nn], 0, 0, 0);
                bf16x8 vf1 = *(const bf16x8*)(Vc + (nn * 16 + lr) * 128 +
                                              (((4 + lg) ^ (lr & 7)) << 4));
                oaccA[nn] = __builtin_amdgcn_mfma_f32_16x16x32_bf16(vf1, pf1,
                                                                    oaccA[nn], 0, 0, 0);
            }
        }
#pragma unroll
        for (int n = 0; n < 4; ++n)
#pragma unroll
            for (int rp = 0; rp < 2; ++rp) {
                u32 rpk;
                asm("v_cvt_pk_bf16_f32 %0, %1, %2"
                    : "=v"(rpk) : "v"(saB[n][2 * rp]), "v"(saB[n][2 * rp + 1]));
                pk[n * 2 + rp] = rpk;
            }
#pragma unroll
        for (int g = 0; g < 4; ++g) {
            int src = (g < 2) ? srcA : srcB;
            u32 a0 = (u32)__shfl((int)pk[0 + (g & 1)], src);
            u32 a1 = (u32)__shfl((int)pk[2 + (g & 1)], src);
            u32 b0 = (u32)__shfl((int)pk[4 + (g & 1)], src);
            u32 b1 = (u32)__shfl((int)pk[6 + (g & 1)], src);
            pb0[g] = hiHalf ? a1 : a0;
            pb1[g] = hiHalf ? b1 : b0;
        }
        {
            bf16x8 pf0 = __builtin_bit_cast(bf16x8, pb0);
            bf16x8 pf1 = __builtin_bit_cast(bf16x8, pb1);
#pragma unroll
            for (int nn = 0; nn < 4; ++nn) {
                bf16x8 vf0 = *(const bf16x8*)(Vc + (nn * 16 + lr) * 128 +
                                              ((lg ^ (lr & 7)) << 4));
                oaccB[nn] = __builtin_amdgcn_mfma_f32_16x16x32_bf16(vf0, pf0,
                                                                    oaccB[nn], 0, 0, 0);
                bf16x8 vf1 = *(const bf16x8*)(Vc + (nn * 16 + lr) * 128 +
                                              (((4 + lg) ^ (lr & 7)) << 4));
                oaccB[nn] = __builtin_amdgcn_mfma_f32_16x16x32_bf16(vf1, pf1,
                                                                    oaccB[nn], 0, 0, 0);
            }
        }
#endif
    }

    // epilogue: normalize, transpose O^T -> O via per-wave LDS scratch
    __syncthreads();   // all waves done reading K/V buffers
#if HAVE_MFMA16
    const float linvA = 1.0f / laccA[0];
    const float linvB = 1.0f / laccB[0];
#else
    float lA = (l4A[0] + l4A[1]) + (l4A[2] + l4A[3]);
    lA += __shfl_xor(lA, 16);
    lA += __shfl_xor(lA, 32);
    float lB = (l4B[0] + l4B[1]) + (l4B[2] + l4B[3]);
    lB += __shfl_xor(lB, 16);
    lB += __shfl_xor(lB, 32);
    const float linvA = 1.0f / lA, linvB = 1.0f / lB;
#endif
    u16* ow = smem + w * (32 * 72);
#pragma unroll
    for (int nn = 0; nn < 4; ++nn)
#pragma unroll
        for (int r = 0; r < 4; ++r) {
            ow[lr * 72 + nn * 16 + 4 * lg + r] = f2bf(oaccA[nn][r] * linvA);
            ow[(16 + lr) * 72 + nn * 16 + 4 * lg + r] = f2bf(oaccB[nn][r] * linvB);
        }
    __syncthreads();
    const int q_ = lane >> 2, d0 = (lane & 3) << 4;
    const u16* orowA = smem + w * (32 * 72) + q_ * 72 + d0;
    const u16* orowB = orowA + 16 * 72;
    u16x8 a0 = *(const u16x8*)(orowA);
    u16x8 a1 = *(const u16x8*)(orowA + 8);
    u16x8 b0 = *(const u16x8*)(orowB);
    u16x8 b1 = *(const u16x8*)(orowB + 8);
    size_t gaddr = ((size_t)bb * 2048 + q0 + w * 32 + q_) * 1024 + h * 64 + d0;
    *(u16x8*)(ao + gaddr) = a0;
    *(u16x8*)(ao + gaddr + 8) = a1;
    *(u16x8*)(ao + gaddr + 16 * 1024) = b0;
    *(u16x8*)(ao + gaddr + 16 * 1024 + 8) = b1;
}

// ---------------------------------------------------------------- launch
extern "C" void kernel_launch(void* const* d_in, const int* in_sizes, int n_in,
                              void* d_out, int out_size, void* d_ws, size_t ws_size,
                              hipStream_t stream) {
    const float* x  = (const float*)d_in[0];
    const float* Wq = (const float*)d_in[1];
    const float* bq = (const float*)d_in[2];
    const float* Wk = (const float*)d_in[3];
    const float* bk = (const float*)d_in[4];
    const float* Wv = (const float*)d_in[5];
    const float* bv = (const float*)d_in[6];
    const float* Wo = (const float*)d_in[7];
    const float* bo = (const float*)d_in[8];

    const size_t MB = 1u << 20;
    if (ws_size < 40 * MB) return;
    char* ws = (char*)d_ws;
    u16* xb    = (u16*)(ws);             // 8MB  [4096][1024] bf16 (reused as ao)
    u16* wqkvt = (u16*)(ws + 8 * MB);    // 6MB  [3072][1024] = [Wq^T;Wk^T;Wv^T]
    u16* wot   = (u16*)(ws + 14 * MB);   // 2MB  Wo^T
    u16* qb    = (u16*)(ws + 16 * MB);   // 8MB  [32][2048][64]
    u16* kb    = (u16*)(ws + 24 * MB);   // 8MB  [32][2048][64]
    u16* vt    = (u16*)(ws + 32 * MB);   // 8MB  [32][64][2048]
    u16* ao    = xb;

    cvt_x_k<<<2048, 256, 0, stream>>>(x, xb);
    cvt_wT4_k<<<dim3(16, 16, 4), 256, 0, stream>>>(Wq, Wk, Wv, Wo, wqkvt, wot);

    gemm_k<0><<<dim3(32, 24), 256, 0, stream>>>(xb, wqkvt, bq, bk, bv,
                                                qb, kb, vt, nullptr);
    attn_k<<<dim3(16, 32), 256, 0, stream>>>(qb, kb, vt, ao);
    gemm_k<1><<<dim3(32, 8), 256, 0, stream>>>(ao, wot, bo, nullptr, nullptr,
                                               nullptr, nullptr, nullptr,
                                               (float*)d_out);
}